// Round 14
// baseline (475.409 us; speedup 1.0000x reference)
//
#include <hip/hip_runtime.h>

typedef unsigned short u16;
typedef unsigned int   u32;
typedef __attribute__((ext_vector_type(8))) short short8;
typedef __attribute__((ext_vector_type(4))) float float4v;

#define N_NODES  16384
#define N_EDGES  65536
#define N_GRAPHS 64

// ---------- helpers ----------
__device__ __forceinline__ float bf(u16 u) { return __uint_as_float(((u32)u) << 16); }
__device__ __forceinline__ u16 fb(float f) {
    u32 b = __float_as_uint(f);
    b += 0x7FFFu + ((b >> 16) & 1u);   // round-to-nearest-even
    return (u16)(b >> 16);
}
__device__ __forceinline__ float silu_f(float x) { return x / (1.f + __expf(-x)); }

// l-grouped msg row layout: row = RB[m] + n*RS[m]
__device__ __constant__ int RBc[16] = {0, 16384,16385,16386, 65536,65537,65538,65539,65540,
                                       147456,147457,147458,147459,147460,147461,147462};
__device__ __constant__ int RSc[16] = {1,3,3,3,5,5,5,5,5,7,7,7,7,7,7,7};

// ---------- zero ----------
__global__ void k_zero(float* p, int n) {
    int i = blockIdx.x * 256 + threadIdx.x;
    if (i < n) p[i] = 0.f;
}

// ---------- input dtype detector (flag=1 => bf16 inputs; f32 gives flag=0) ----------
__global__ void k_detect(const void* x, int* flag) {
    __shared__ int f;
    if (threadIdx.x == 0) f = 0;
    __syncthreads();
    const u16* p = (const u16*)x;
    for (int i = threadIdx.x; i < 4096; i += 256)
        if (p[i] == 0x3F80u && (i & 1) == 0) f = 1;
    __syncthreads();
    if (threadIdx.x == 0) *flag = f;
}

// ---------- convert 12 weight arrays to canonical bf16 copies ----------
struct CvtArgs { const void* src[12]; int n[12]; };
__global__ void k_convert(CvtArgs a, u16* dst, const int* flag) {
    int fl = *flag;
    size_t base = 0;
    int stride = gridDim.x * 256;
    for (int q = 0; q < 12; q++) {
        int n = a.n[q];
        for (int i = blockIdx.x * 256 + threadIdx.x; i < n; i += stride) {
            u16 v;
            if (fl) v = ((const u16*)a.src[q])[i];
            else    v = fb(((const float*)a.src[q])[i]);
            if (q == 6) {
                int slab = i >> 14, rem = i & 16383, kk = rem >> 7, nn = rem & 127;
                dst[base + slab * 16384 + nn * 128 + kk] = v;
            } else if (q == 3 || q == 4) {
                int tq = i >> 12, rem = i & 4095, kk = rem >> 6, nn = rem & 63;
                dst[base + tq * 4096 + nn * 64 + kk] = v;
            } else if (q == 5) {
                int tq = i >> 15, rem = i & 32767, kk = rem >> 9, nn = rem & 511;
                dst[base + tq * 32768 + nn * 64 + kk] = v;
            } else if (q == 1 || q == 11) {
                int tq = i >> 14, rem = i & 16383, kk = rem >> 7, k = rem & 127;
                dst[base + tq * 16384 + k * 128 + kk] = v;
            } else if (q == 7) {
                int tq = i >= 163840 ? 1 : 0, rem = i - tq * 163840;
                int sp = rem >> 14, r2 = rem & 16383, kk = r2 >> 7, k = r2 & 127;
                dst[base + ((size_t)tq * 10 + sp) * 16384 + k * 128 + kk] = v;
            } else {
                dst[base + i] = v;
            }
        }
        base += n;
    }
}

// ---------- species + LDS-aggregated histogram ----------
__global__ __launch_bounds__(256) void k_species(const void* x, int* species, int* shist,
                                                 const int* flag) {
    __shared__ int lh[10];
    int tid = threadIdx.x;
    if (tid < 10) lh[tid] = 0;
    __syncthreads();
    int n = blockIdx.x * 256 + tid;
    int sp = 0;
    if (*flag) {
        const u16* xp = (const u16*)x + (size_t)n * 10;
        for (int z = 0; z < 10; z++)
            if (bf(xp[z]) > 0.5f) { sp = z; break; }
    } else {
        const float* xp = (const float*)x + (size_t)n * 10;
        for (int z = 0; z < 10; z++)
            if (xp[z] > 0.5f) { sp = z; break; }
    }
    species[n] = sp;
    atomicAdd(&lh[sp], 1);
    __syncthreads();
    if (tid < 10) atomicAdd(&shist[tid], lh[tid]);
}

// ---------- embedding fill ----------
__global__ __launch_bounds__(256) void k_embed(const int* species, const u16* Wemb, float* nf) {
    int i = blockIdx.x * 256 + threadIdx.x;
    int n = i >> 7, k = i & 127;
    nf[i] = bf(Wemb[species[n] * 128 + k]) * 0.31622776601683794f;
}

// ---------- species scan ----------
__global__ void k_spscan(const int* shist, int* spoffs, int* spcursor) {
    if (threadIdx.x == 0) {
        int run = 0;
        for (int s = 0; s < 10; s++) { spoffs[s] = run; spcursor[s] = run; run += shist[s]; }
        spoffs[10] = run;
    }
}

// ---------- species sort: LDS-aggregated ----------
__global__ __launch_bounds__(256) void k_spsort(const int* species, int* spcursor, int* perm) {
    __shared__ int lcnt[10], lbase[10], lrank[10];
    int tid = threadIdx.x;
    if (tid < 10) { lcnt[tid] = 0; lrank[tid] = 0; }
    __syncthreads();
    int n = blockIdx.x * 256 + tid;
    int sp = species[n];
    atomicAdd(&lcnt[sp], 1);
    __syncthreads();
    if (tid < 10) lbase[tid] = atomicAdd(&spcursor[tid], lcnt[tid]);
    __syncthreads();
    int r = atomicAdd(&lrank[sp], 1);
    perm[lbase[sp] + r] = n;
}

// ---------- edge prep: SH + bessel + histogram ----------
__global__ __launch_bounds__(256) void k_prep_edges(const int* eidx, const void* pos,
                                                    float* esh, float* ef, int* hist,
                                                    const int* flag) {
    int e = blockIdx.x * 256 + threadIdx.x;
    int j = eidx[e], i = eidx[N_EDGES + e];
    float vx, vy, vz;
    if (*flag) {
        const u16* p = (const u16*)pos;
        vx = bf(p[j * 3 + 0]) - bf(p[i * 3 + 0]);
        vy = bf(p[j * 3 + 1]) - bf(p[i * 3 + 1]);
        vz = bf(p[j * 3 + 2]) - bf(p[i * 3 + 2]);
    } else {
        const float* p = (const float*)pos;
        vx = p[j * 3 + 0] - p[i * 3 + 0];
        vy = p[j * 3 + 1] - p[i * 3 + 1];
        vz = p[j * 3 + 2] - p[i * 3 + 2];
    }
    float r = sqrtf(vx * vx + vy * vy + vz * vz + 1e-12f);
    float rinv = 1.f / r;
    float X = vx * rinv, Y = vy * rinv, Z = vz * rinv;
    float x2 = X * X, y2 = Y * Y, z2 = Z * Z;
    const float s3 = 1.7320508075688772f, s15 = 3.872983346207417f, s5 = 2.23606797749979f;
    const float s35_8 = 2.091650066335189f, s105 = 10.246950765959598f;
    const float s21_8 = 1.6201851746019651f, s7 = 2.6457513110645907f;
    float Yh[16];
    Yh[0] = 1.f; Yh[1] = s3 * X; Yh[2] = s3 * Y; Yh[3] = s3 * Z;
    Yh[4] = s15 * X * Y; Yh[5] = s15 * Y * Z; Yh[6] = 0.5f * s5 * (3.f * z2 - 1.f);
    Yh[7] = s15 * X * Z; Yh[8] = 0.5f * s15 * (x2 - y2);
    Yh[9] = s35_8 * Y * (3.f * x2 - y2); Yh[10] = s105 * X * Y * Z;
    Yh[11] = s21_8 * Y * (5.f * z2 - 1.f); Yh[12] = 0.5f * s7 * Z * (5.f * z2 - 3.f);
    Yh[13] = s21_8 * X * (5.f * z2 - 1.f); Yh[14] = 0.5f * s105 * Z * (x2 - y2);
    Yh[15] = s35_8 * X * (x2 - 3.f * y2);
#pragma unroll
    for (int m = 0; m < 16; m++) esh[e * 16 + m] = Yh[m];

    float u = r * 0.2f;
    float fc = 0.f;
    if (u < 1.f) {
        float u2 = u * u, u4 = u2 * u2, u5 = u4 * u, u6 = u5 * u, u7 = u6 * u;
        fc = 1.f - 21.f * u5 + 35.f * u6 - 15.f * u7;
    }
    const float pref = 0.6324555320336759f; // sqrt(2/5)
#pragma unroll
    for (int nn = 1; nn <= 8; nn++)
        ef[e * 8 + nn - 1] = pref * sinf((float)nn * 3.14159265358979323846f * u) * rinv * fc;

    atomicAdd(&hist[i], 1);
}

// ---------- exclusive scan of 16384 counts ----------
__global__ __launch_bounds__(1024) void k_scan(const int* hist, int* offs, int* cursor) {
    __shared__ int part[1024];
    int t = threadIdx.x;
    int base = t * 16;
    int v[16]; int s = 0;
#pragma unroll
    for (int q = 0; q < 16; q++) { v[q] = hist[base + q]; s += v[q]; }
    part[t] = s;
    __syncthreads();
    for (int d = 1; d < 1024; d <<= 1) {
        int add = (t >= d) ? part[t - d] : 0;
        __syncthreads();
        part[t] += add;
        __syncthreads();
    }
    int run = part[t] - s; // exclusive
#pragma unroll
    for (int q = 0; q < 16; q++) { offs[base + q] = run; cursor[base + q] = run; run += v[q]; }
    if (t == 1023) offs[16384] = run;
}

// ---------- counting-sort scatter ----------
__global__ __launch_bounds__(256) void k_sort(const int* eidx, int* cursor, int* sorted) {
    int e = blockIdx.x * 256 + threadIdx.x;
    int i = eidx[N_EDGES + e];
    int p = atomicAdd(&cursor[i], 1);
    sorted[p] = e;
}

// ---------- up + sc via species-grouped MFMA GEMM ----------
__global__ __launch_bounds__(256) void k_upsc(int t, const float* nf, const int* perm,
                                              const int* spoffs, const u16* WupT,
                                              const u16* WskipT, u16* up, float* sc) {
    __shared__ u16 wu[16384];
    __shared__ u16 wsk[16384];
    int s = blockIdx.y;
    int rstart = spoffs[s] + blockIdx.x * 64;
    int rend = spoffs[s + 1];
    if (rstart >= rend) return;
    int tid = threadIdx.x;
    const u16* wg1 = WupT + (size_t)t * 16384;
    const u16* wg2 = WskipT + ((size_t)t * 10 + s) * 16384;
#pragma unroll
    for (int p = 0; p < 8; p++) {
        int slot = p * 256 + tid;
        int nt = slot >> 8, ks = (slot >> 6) & 3, ln = slot & 63;
        int nn = nt * 16 + (ln & 15), k0 = ks * 32 + (ln >> 4) * 8;
        *(uint4*)&wu[slot * 8]  = *(const uint4*)&wg1[nn * 128 + k0];
        *(uint4*)&wsk[slot * 8] = *(const uint4*)&wg2[nn * 128 + k0];
    }
    __syncthreads();

    int wave = tid >> 6, lane = tid & 63;
    int m16 = lane & 15, quad = lane >> 4;
    int arow = rstart + wave * 16 + m16;
    int anode = perm[arow < rend ? arow : rstart];
    short8 afr[4];
#pragma unroll
    for (int ks = 0; ks < 4; ks++) {
        const float* ap = nf + (size_t)anode * 128 + ks * 32 + quad * 8;
        short8 v;
#pragma unroll
        for (int q = 0; q < 8; q++) v[q] = (short)fb(ap[q]);
        afr[ks] = v;
    }

    float4v accU[8], accS[8];
#pragma unroll
    for (int nt = 0; nt < 8; nt++) {
        accU[nt] = (float4v){0.f, 0.f, 0.f, 0.f};
        accS[nt] = (float4v){0.f, 0.f, 0.f, 0.f};
#pragma unroll
        for (int ks = 0; ks < 4; ks++) {
            short8 b1 = *(const short8*)&wu[((nt * 4 + ks) * 64 + lane) * 8];
            short8 b2 = *(const short8*)&wsk[((nt * 4 + ks) * 64 + lane) * 8];
            accU[nt] = __builtin_amdgcn_mfma_f32_16x16x32_bf16(afr[ks], b1, accU[nt], 0, 0, 0);
            accS[nt] = __builtin_amdgcn_mfma_f32_16x16x32_bf16(afr[ks], b2, accS[nt], 0, 0, 0);
        }
    }

    int crow0 = rstart + wave * 16 + quad * 4;
    int cnode[4]; int cvalid[4];
#pragma unroll
    for (int r = 0; r < 4; r++) {
        int rr = crow0 + r;
        cvalid[r] = rr < rend;
        cnode[r] = perm[cvalid[r] ? rr : rstart];
    }
#pragma unroll
    for (int nt = 0; nt < 8; nt++) {
        int col = nt * 16 + m16;
#pragma unroll
        for (int r = 0; r < 4; r++) {
            if (cvalid[r]) {
                up[(size_t)cnode[r] * 128 + col] = fb(accU[nt][r] * 0.08838834764831845f);
                sc[(size_t)cnode[r] * 128 + col] = accS[nt][r] * 0.027950849718747373f;
            }
        }
    }
}

// ---------- radial MLP via MFMA (r12 version, proven 46.3 us) ----------
#define HS 68
__global__ __launch_bounds__(64) void k_radial(int t, const float* ef, const u16* Wr0,
                                               const u16* Wr1T, const u16* Wr2T,
                                               const u16* Wr3T, u16* tpw) {
    __shared__ u16 w0s[512];
    __shared__ u16 hbuf[2176];   // h0 [0,1088) | h1 [1088,2176); L3 staging aliases all
    int tid = threadIdx.x;
    const u16* w0p = Wr0 + t * 512;
    *(uint4*)&w0s[tid * 8] = *(const uint4*)&w0p[tid * 8];
    __syncthreads();

    int lane = tid;
    int m16 = lane & 15, quad = lane >> 4;
    int E0 = blockIdx.x * 16;
    u16* h0 = &hbuf[0];
    u16* h1 = &hbuf[1088];

    // ---- L0 (VALU, K=8) ----
    float efv[8];
    {
        const float* ep = ef + (size_t)(E0 + m16) * 8;
        float4 e0 = *(const float4*)ep, e1 = *(const float4*)(ep + 4);
        efv[0] = e0.x; efv[1] = e0.y; efv[2] = e0.z; efv[3] = e0.w;
        efv[4] = e1.x; efv[5] = e1.y; efv[6] = e1.z; efv[7] = e1.w;
    }
#pragma unroll
    for (int o = 0; o < 16; o++) {
        int oc = quad * 16 + o;
        float a = 0.f;
#pragma unroll
        for (int b = 0; b < 8; b++) a += efv[b] * bf(w0s[b * 64 + oc]);
        h0[m16 * HS + oc] = fb(silu_f(a * 0.35355339059327373f));
    }
    __syncthreads();

    // ---- L1 (MFMA 16x16x32, K=64, N=64) ----
    const u16* w1p = Wr1T + t * 4096;
    short8 afr[2];
    afr[0] = *(const short8*)&h0[m16 * HS + quad * 8];
    afr[1] = *(const short8*)&h0[m16 * HS + 32 + quad * 8];
    {
        float4v acc[4];
#pragma unroll
        for (int nt = 0; nt < 4; nt++) {
            acc[nt] = (float4v){0.f, 0.f, 0.f, 0.f};
#pragma unroll
            for (int ks = 0; ks < 2; ks++) {
                short8 bfr = *(const short8*)&w1p[(nt * 16 + m16) * 64 + ks * 32 + quad * 8];
                acc[nt] = __builtin_amdgcn_mfma_f32_16x16x32_bf16(afr[ks], bfr, acc[nt], 0, 0, 0);
            }
        }
#pragma unroll
        for (int nt = 0; nt < 4; nt++)
#pragma unroll
            for (int r = 0; r < 4; r++)
                h1[(quad * 4 + r) * HS + nt * 16 + m16] = fb(silu_f(acc[nt][r] * 0.125f));
    }
    __syncthreads();

    // ---- L2 (MFMA, K=64, N=64) ----
    const u16* w2p = Wr2T + t * 4096;
    afr[0] = *(const short8*)&h1[m16 * HS + quad * 8];
    afr[1] = *(const short8*)&h1[m16 * HS + 32 + quad * 8];
    {
        float4v acc[4];
#pragma unroll
        for (int nt = 0; nt < 4; nt++) {
            acc[nt] = (float4v){0.f, 0.f, 0.f, 0.f};
#pragma unroll
            for (int ks = 0; ks < 2; ks++) {
                short8 bfr = *(const short8*)&w2p[(nt * 16 + m16) * 64 + ks * 32 + quad * 8];
                acc[nt] = __builtin_amdgcn_mfma_f32_16x16x32_bf16(afr[ks], bfr, acc[nt], 0, 0, 0);
            }
        }
#pragma unroll
        for (int nt = 0; nt < 4; nt++)
#pragma unroll
            for (int r = 0; r < 4; r++)
                h0[(quad * 4 + r) * HS + nt * 16 + m16] = fb(silu_f(acc[nt][r] * 0.125f));
    }
    __syncthreads();

    // ---- L3 (MFMA, K=64, N=512), chunked 4x128; staging aliases hbuf ----
    const u16* w3p = Wr3T + t * 32768;
    afr[0] = *(const short8*)&h0[m16 * HS + quad * 8];
    afr[1] = *(const short8*)&h0[m16 * HS + 32 + quad * 8];
    u16* stw = &hbuf[0];
    for (int cc = 0; cc < 4; cc++) {
#pragma unroll
        for (int nt8 = 0; nt8 < 8; nt8++) {
            int nt = cc * 8 + nt8;
            float4v a3 = (float4v){0.f, 0.f, 0.f, 0.f};
#pragma unroll
            for (int ks = 0; ks < 2; ks++) {
                short8 bfr = *(const short8*)&w3p[(nt * 16 + m16) * 64 + ks * 32 + quad * 8];
                a3 = __builtin_amdgcn_mfma_f32_16x16x32_bf16(afr[ks], bfr, a3, 0, 0, 0);
            }
#pragma unroll
            for (int r = 0; r < 4; r++)
                stw[(quad * 4 + r) * 136 + nt8 * 16 + m16] = fb(a3[r] * 0.125f);
        }
        __syncthreads();
#pragma unroll
        for (int st = 0; st < 4; st++) {
            int edge = st * 4 + quad;
            uint4 v = *(const uint4*)&stw[edge * 136 + m16 * 8];
            *(uint4*)&tpw[(size_t)(E0 + edge) * 512 + cc * 128 + m16 * 8] = v;
        }
        __syncthreads();
    }
}
#undef HS

// ---------- message accumulation -> l-grouped global msg (bf16) ----------
__global__ __launch_bounds__(256) void k_msg(const int* offs, const int* sorted,
                                             const int* eidx, const float* esh,
                                             const u16* up, const u16* tpw, u16* msgA) {
    const int LM[16] = {0,1,1,1,2,2,2,2,2,3,3,3,3,3,3,3};
    int tid = threadIdx.x;
    int nsub = tid >> 5;
    int kq = tid & 31;
    int k4 = kq * 4;
    int n = blockIdx.x * 8 + nsub;

    float acc[16][4];
#pragma unroll
    for (int m = 0; m < 16; m++)
#pragma unroll
        for (int q = 0; q < 4; q++) acc[m][q] = 0.f;
    int s = offs[n], e1 = offs[n + 1];
    for (int idx = s; idx < e1; idx++) {
        int e = sorted[idx];
        int j = eidx[e];
        ushort4 uu = *(const ushort4*)(up + (size_t)j * 128 + k4);
        float u0 = bf(uu.x), u1 = bf(uu.y), u2 = bf(uu.z), u3 = bf(uu.w);
        float4 sA = *(const float4*)(esh + (size_t)e * 16);
        float4 sB = *(const float4*)(esh + (size_t)e * 16 + 4);
        float4 sC = *(const float4*)(esh + (size_t)e * 16 + 8);
        float4 sD = *(const float4*)(esh + (size_t)e * 16 + 12);
        float sh[16] = {sA.x, sA.y, sA.z, sA.w, sB.x, sB.y, sB.z, sB.w,
                        sC.x, sC.y, sC.z, sC.w, sD.x, sD.y, sD.z, sD.w};
        float p[4][4];
#pragma unroll
        for (int l = 0; l < 4; l++) {
            ushort4 tp = *(const ushort4*)(tpw + (size_t)e * 512 + l * 128 + k4);
            p[l][0] = u0 * bf(tp.x); p[l][1] = u1 * bf(tp.y);
            p[l][2] = u2 * bf(tp.z); p[l][3] = u3 * bf(tp.w);
        }
#pragma unroll
        for (int m = 0; m < 16; m++) {
            int l = LM[m];
            acc[m][0] += sh[m] * p[l][0]; acc[m][1] += sh[m] * p[l][1];
            acc[m][2] += sh[m] * p[l][2]; acc[m][3] += sh[m] * p[l][3];
        }
    }
#pragma unroll
    for (int m = 0; m < 16; m++) {
        int row = RBc[m] + n * RSc[m];
        ushort4 o;
        o.x = fb(acc[m][0] * 0.1f); o.y = fb(acc[m][1] * 0.1f);
        o.z = fb(acc[m][2] * 0.1f); o.w = fb(acc[m][3] * 0.1f);
        *(ushort4*)(msgA + (size_t)row * 128 + k4) = o;
    }
}

// ---------- FUSED: A-GEMM + invariants + product basis -> bvec ----------
// 4 waves/block, 64 nodes/block (wave handles 16 nodes). For each l: stage W_l
// in LDS frag-order; for each m of that l: A-frag rows = the 16 nodes' msg rows;
// MFMA gives, on each lane, D[node=quad*4+r][ch=nt*16+m16] — SAME (node,ch)
// pairs for every m => A0 and inv2[l] accumulate in registers, A never hits HBM.
__global__ __launch_bounds__(256) void k_gemmAb(int t, const u16* msgA, const u16* WlinT,
                                                const int* species,
                                                const u16* Wp1, const u16* Wp2, const u16* Wp3,
                                                u16* bvec) {
    __shared__ u16 wfr[16384];
    int tid = threadIdx.x;
    int wave = tid >> 6, lane = tid & 63;
    int m16 = lane & 15, quad = lane >> 4;
    int n0w = blockIdx.x * 64 + wave * 16;
    const float sAc = 0.08838834764831845f;

    float A0[8][4];
    float inv2[4][8][4];
#pragma unroll
    for (int l = 0; l < 4; l++)
#pragma unroll
        for (int nt = 0; nt < 8; nt++)
#pragma unroll
            for (int r = 0; r < 4; r++) inv2[l][nt][r] = 0.f;

    const int ms_[4] = {0, 1, 4, 9}, me_[4] = {1, 4, 9, 16};
#pragma unroll
    for (int l = 0; l < 4; l++) {
        __syncthreads();   // protect previous l's wfr reads
        const u16* wg = WlinT + ((size_t)t * 4 + l) * 16384;
#pragma unroll
        for (int p = 0; p < 8; p++) {
            int slot = p * 256 + tid;
            int nt = slot >> 8, ks = (slot >> 6) & 3, ln = slot & 63;
            int nn = nt * 16 + (ln & 15), k0 = ks * 32 + (ln >> 4) * 8;
            *(uint4*)&wfr[slot * 8] = *(const uint4*)&wg[nn * 128 + k0];
        }
        __syncthreads();
#pragma unroll
        for (int m = ms_[l]; m < me_[l]; m++) {
            int rowa = RBc[m] + (n0w + m16) * RSc[m];
            const u16* ap = msgA + (size_t)rowa * 128 + quad * 8;
            short8 afr[4];
#pragma unroll
            for (int ks = 0; ks < 4; ks++) afr[ks] = *(const short8*)(ap + ks * 32);
#pragma unroll
            for (int nt = 0; nt < 8; nt++) {
                float4v acc = (float4v){0.f, 0.f, 0.f, 0.f};
#pragma unroll
                for (int ks = 0; ks < 4; ks++) {
                    short8 bfr = *(const short8*)&wfr[((nt * 4 + ks) * 64 + lane) * 8];
                    acc = __builtin_amdgcn_mfma_f32_16x16x32_bf16(afr[ks], bfr, acc, 0, 0, 0);
                }
#pragma unroll
                for (int r = 0; r < 4; r++) {
                    float a = acc[r] * sAc;
                    if (m == 0) A0[nt][r] = a;
                    inv2[l][nt][r] += a * a;
                }
            }
        }
    }

    // ---- epilogue: b = w1*A0 + w2.inv2 + (w3.inv2)*A0 -> bvec ----
#pragma unroll
    for (int r = 0; r < 4; r++) {
        int n = n0w + quad * 4 + r;
        int sp = species[n];
        const u16* p1 = Wp1 + ((size_t)t * 10 + sp) * 128;
        const u16* p2 = Wp2 + ((size_t)t * 10 + sp) * 4 * 128;
        const u16* p3 = Wp3 + ((size_t)t * 10 + sp) * 4 * 128;
#pragma unroll
        for (int nt = 0; nt < 8; nt++) {
            int ch = nt * 16 + m16;
            float w1 = bf(p1[ch]);
            float s2 = 0.f, s3 = 0.f;
#pragma unroll
            for (int l = 0; l < 4; l++) {
                s2 += bf(p2[l * 128 + ch]) * inv2[l][nt][r];
                s3 += bf(p3[l * 128 + ch]) * inv2[l][nt][r];
            }
            bvec[(size_t)n * 128 + ch] = fb(w1 * A0[nt][r] + s2 + s3 * A0[nt][r]);
        }
    }
}

// ---------- nf = bvec @ WplT / sqrt(128) + sc ----------
__global__ __launch_bounds__(256) void k_gemm_nf(int t, const u16* bvec, const u16* WplT,
                                                 const float* sc, float* nf) {
    __shared__ u16 wfr[16384];
    int rb0 = blockIdx.x * 64;
    int tid = threadIdx.x;
    const u16* wg = WplT + (size_t)t * 16384;
#pragma unroll
    for (int p = 0; p < 8; p++) {
        int slot = p * 256 + tid;
        int nt = slot >> 8, ks = (slot >> 6) & 3, ln = slot & 63;
        int nn = nt * 16 + (ln & 15), k0 = ks * 32 + (ln >> 4) * 8;
        *(uint4*)&wfr[slot * 8] = *(const uint4*)&wg[nn * 128 + k0];
    }
    __syncthreads();

    int wave = tid >> 6, lane = tid & 63;
    int m16 = lane & 15, quad = lane >> 4;
    int rowa = rb0 + wave * 16 + m16;
    const u16* ap = bvec + (size_t)rowa * 128 + quad * 8;
    short8 afr[4];
#pragma unroll
    for (int ks = 0; ks < 4; ks++) afr[ks] = *(const short8*)(ap + ks * 32);

    float4v acc[8];
#pragma unroll
    for (int nt = 0; nt < 8; nt++) acc[nt] = (float4v){0.f, 0.f, 0.f, 0.f};
#pragma unroll
    for (int nt = 0; nt < 8; nt++)
#pragma unroll
        for (int ks = 0; ks < 4; ks++) {
            short8 bfr = *(const short8*)&wfr[((nt * 4 + ks) * 64 + lane) * 8];
            acc[nt] = __builtin_amdgcn_mfma_f32_16x16x32_bf16(afr[ks], bfr, acc[nt], 0, 0, 0);
        }

    const float sAc = 0.08838834764831845f;
    int rowc = rb0 + wave * 16 + quad * 4;
#pragma unroll
    for (int nt = 0; nt < 8; nt++) {
        int col = nt * 16 + m16;
#pragma unroll
        for (int r = 0; r < 4; r++) {
            size_t idx = (size_t)(rowc + r) * 128 + col;
            nf[idx] = acc[nt][r] * sAc + sc[idx];
        }
    }
}

// ---------- graph readout: 8 nodes/block, register segment-sum + atomic flush ----------
__global__ __launch_bounds__(128) void k_reduce(const float* nf, const int* batch,
                                                float* env, float* cnt) {
    int k = threadIdx.x;
    int n0 = blockIdx.x * 8;
    float run = 0.f;
    int c = 0;
    int gp = batch[n0];
    for (int nn = 0; nn < 8; nn++) {
        int n = n0 + nn;
        int g = batch[n];
        if (g != gp) {
            atomicAdd(&env[gp * 128 + k], run);
            if (k == 0) atomicAdd(&cnt[gp], (float)c);
            run = 0.f; c = 0; gp = g;
        }
        run += nf[(size_t)n * 128 + k];
        c++;
    }
    atomicAdd(&env[gp * 128 + k], run);
    if (k == 0) atomicAdd(&cnt[gp], (float)c);
}

// ---------- final: output float32 ----------
__global__ void k_final(const float* env, const float* cnt, float* out) {
    int i = blockIdx.x * 256 + threadIdx.x;
    if (i < N_GRAPHS * 128) out[i] = env[i] / fmaxf(cnt[i >> 7], 1.f);
}

// ---------- launch ----------
extern "C" void kernel_launch(void* const* d_in, const int* in_sizes, int n_in,
                              void* d_out, int out_size, void* d_ws, size_t ws_size,
                              hipStream_t stream) {
    (void)in_sizes; (void)n_in; (void)out_size; (void)ws_size;
    const void* x    = d_in[0];
    const void* pos  = d_in[1];
    const int* eidx  = (const int*)d_in[14];
    const int* batch = (const int*)d_in[15];

    char* base = (char*)d_ws;
    size_t cur = 0;
    auto alloc = [&](size_t bytes) -> void* {
        void* p = base + cur;
        cur = (cur + bytes + 255) & ~(size_t)255;
        return p;
    };
    int*   flag    = (int*)alloc(4);
    u16*   cvt     = (u16*)alloc((size_t)631552 * 2);
    int*   species = (int*)alloc((size_t)N_NODES * 4);
    int*   shist   = (int*)alloc(64);
    int*   spoffs  = (int*)alloc(64);
    int*   spcursor= (int*)alloc(64);
    int*   perm    = (int*)alloc((size_t)N_NODES * 4);
    int*   hist    = (int*)alloc((size_t)N_NODES * 4);
    int*   offs    = (int*)alloc((size_t)(N_NODES + 1) * 4);
    int*   cursor  = (int*)alloc((size_t)N_NODES * 4);
    int*   sorted  = (int*)alloc((size_t)N_EDGES * 4);
    float* env     = (float*)alloc((size_t)N_GRAPHS * 128 * 4);
    float* cnt     = (float*)alloc((size_t)N_GRAPHS * 4);
    float* nf      = (float*)alloc((size_t)N_NODES * 128 * 4);
    u16*   up      = (u16*)alloc((size_t)N_NODES * 128 * 2);
    u16*   bvec    = (u16*)alloc((size_t)N_NODES * 128 * 2);
    float* sc      = (float*)alloc((size_t)N_NODES * 128 * 4);
    float* ef      = (float*)alloc((size_t)N_EDGES * 8 * 4);
    float* esh     = (float*)alloc((size_t)N_EDGES * 16 * 4);
    u16*   tpw     = (u16*)alloc((size_t)N_EDGES * 512 * 2);
    u16*   msgA    = (u16*)alloc((size_t)262144 * 128 * 2);

    static const int cn[12] = {1280, 32768, 1024, 8192, 8192, 65536,
                               131072, 327680, 2560, 10240, 10240, 32768};
    CvtArgs ca;
    size_t off[13]; off[0] = 0;
    for (int q = 0; q < 12; q++) { ca.src[q] = d_in[2 + q]; ca.n[q] = cn[q]; off[q + 1] = off[q] + cn[q]; }
    u16* cWemb  = cvt + off[0];
    u16* cWupT  = cvt + off[1];
    u16* cWr0   = cvt + off[2];
    u16* cWr1T  = cvt + off[3];
    u16* cWr2T  = cvt + off[4];
    u16* cWr3T  = cvt + off[5];
    u16* cWlinT = cvt + off[6];
    u16* cWskipT= cvt + off[7];
    u16* cWp1   = cvt + off[8];
    u16* cWp2   = cvt + off[9];
    u16* cWp3   = cvt + off[10];
    u16* cWplT  = cvt + off[11];

    k_detect<<<1, 256, 0, stream>>>(x, flag);
    k_convert<<<256, 256, 0, stream>>>(ca, cvt, flag);
    k_zero<<<64, 256, 0, stream>>>((float*)hist, N_NODES);
    k_zero<<<1, 64, 0, stream>>>((float*)shist, 16);
    k_zero<<<32, 256, 0, stream>>>(env, N_GRAPHS * 128);
    k_zero<<<1, 256, 0, stream>>>(cnt, N_GRAPHS);
    k_species<<<N_NODES / 256, 256, 0, stream>>>(x, species, shist, flag);
    k_embed<<<N_NODES * 128 / 256, 256, 0, stream>>>(species, cWemb, nf);
    k_spscan<<<1, 64, 0, stream>>>(shist, spoffs, spcursor);
    k_spsort<<<N_NODES / 256, 256, 0, stream>>>(species, spcursor, perm);
    k_prep_edges<<<N_EDGES / 256, 256, 0, stream>>>(eidx, pos, esh, ef, hist, flag);
    k_scan<<<1, 1024, 0, stream>>>(hist, offs, cursor);
    k_sort<<<N_EDGES / 256, 256, 0, stream>>>(eidx, cursor, sorted);

    for (int t = 0; t < 2; t++) {
        k_upsc<<<dim3(256, 10), 256, 0, stream>>>(t, nf, perm, spoffs, cWupT, cWskipT, up, sc);
        k_radial<<<N_EDGES / 16, 64, 0, stream>>>(t, ef, cWr0, cWr1T, cWr2T, cWr3T, tpw);
        k_msg<<<N_NODES / 8, 256, 0, stream>>>(offs, sorted, eidx, esh, up, tpw, msgA);
        k_gemmAb<<<N_NODES / 64, 256, 0, stream>>>(t, msgA, cWlinT, species,
                                                   cWp1, cWp2, cWp3, bvec);
        k_gemm_nf<<<N_NODES / 64, 256, 0, stream>>>(t, bvec, cWplT, sc, nf);
    }
    k_reduce<<<N_NODES / 8, 128, 0, stream>>>(nf, batch, env, cnt);
    k_final<<<32, 256, 0, stream>>>(env, cnt, (float*)d_out);
}

// Round 15
// 449.008 us; speedup vs baseline: 1.0588x; 1.0588x over previous
//
#include <hip/hip_runtime.h>

typedef unsigned short u16;
typedef unsigned int   u32;
typedef __attribute__((ext_vector_type(8))) short short8;
typedef __attribute__((ext_vector_type(4))) float float4v;

#define N_NODES  16384
#define N_EDGES  65536
#define N_GRAPHS 64

// ---------- helpers ----------
__device__ __forceinline__ float bf(u16 u) { return __uint_as_float(((u32)u) << 16); }
__device__ __forceinline__ u16 fb(float f) {
    u32 b = __float_as_uint(f);
    b += 0x7FFFu + ((b >> 16) & 1u);   // round-to-nearest-even
    return (u16)(b >> 16);
}
__device__ __forceinline__ float silu_f(float x) { return x / (1.f + __expf(-x)); }

// l-grouped msg row layout: row = RB[m] + n*RS[m]
__device__ __constant__ int RBc[16] = {0, 16384,16385,16386, 65536,65537,65538,65539,65540,
                                       147456,147457,147458,147459,147460,147461,147462};
__device__ __constant__ int RSc[16] = {1,3,3,3,5,5,5,5,5,7,7,7,7,7,7,7};

// ---------- zero ----------
__global__ void k_zero(float* p, int n) {
    int i = blockIdx.x * 256 + threadIdx.x;
    if (i < n) p[i] = 0.f;
}

// ---------- input dtype detector (flag=1 => bf16 inputs; f32 gives flag=0) ----------
__global__ void k_detect(const void* x, int* flag) {
    __shared__ int f;
    if (threadIdx.x == 0) f = 0;
    __syncthreads();
    const u16* p = (const u16*)x;
    for (int i = threadIdx.x; i < 4096; i += 256)
        if (p[i] == 0x3F80u && (i & 1) == 0) f = 1;
    __syncthreads();
    if (threadIdx.x == 0) *flag = f;
}

// ---------- convert 12 weight arrays to canonical bf16 copies ----------
struct CvtArgs { const void* src[12]; int n[12]; };
__global__ void k_convert(CvtArgs a, u16* dst, const int* flag) {
    int fl = *flag;
    size_t base = 0;
    int stride = gridDim.x * 256;
    for (int q = 0; q < 12; q++) {
        int n = a.n[q];
        for (int i = blockIdx.x * 256 + threadIdx.x; i < n; i += stride) {
            u16 v;
            if (fl) v = ((const u16*)a.src[q])[i];
            else    v = fb(((const float*)a.src[q])[i]);
            if (q == 6) {
                int slab = i >> 14, rem = i & 16383, kk = rem >> 7, nn = rem & 127;
                dst[base + slab * 16384 + nn * 128 + kk] = v;
            } else if (q == 3 || q == 4) {
                int tq = i >> 12, rem = i & 4095, kk = rem >> 6, nn = rem & 63;
                dst[base + tq * 4096 + nn * 64 + kk] = v;
            } else if (q == 5) {
                int tq = i >> 15, rem = i & 32767, kk = rem >> 9, nn = rem & 511;
                dst[base + tq * 32768 + nn * 64 + kk] = v;
            } else if (q == 1 || q == 11) {
                int tq = i >> 14, rem = i & 16383, kk = rem >> 7, k = rem & 127;
                dst[base + tq * 16384 + k * 128 + kk] = v;
            } else if (q == 7) {
                int tq = i >= 163840 ? 1 : 0, rem = i - tq * 163840;
                int sp = rem >> 14, r2 = rem & 16383, kk = r2 >> 7, k = r2 & 127;
                dst[base + ((size_t)tq * 10 + sp) * 16384 + k * 128 + kk] = v;
            } else {
                dst[base + i] = v;
            }
        }
        base += n;
    }
}

// ---------- species + LDS-aggregated histogram ----------
__global__ __launch_bounds__(256) void k_species(const void* x, int* species, int* shist,
                                                 const int* flag) {
    __shared__ int lh[10];
    int tid = threadIdx.x;
    if (tid < 10) lh[tid] = 0;
    __syncthreads();
    int n = blockIdx.x * 256 + tid;
    int sp = 0;
    if (*flag) {
        const u16* xp = (const u16*)x + (size_t)n * 10;
        for (int z = 0; z < 10; z++)
            if (bf(xp[z]) > 0.5f) { sp = z; break; }
    } else {
        const float* xp = (const float*)x + (size_t)n * 10;
        for (int z = 0; z < 10; z++)
            if (xp[z] > 0.5f) { sp = z; break; }
    }
    species[n] = sp;
    atomicAdd(&lh[sp], 1);
    __syncthreads();
    if (tid < 10) atomicAdd(&shist[tid], lh[tid]);
}

// ---------- embedding fill ----------
__global__ __launch_bounds__(256) void k_embed(const int* species, const u16* Wemb, float* nf) {
    int i = blockIdx.x * 256 + threadIdx.x;
    int n = i >> 7, k = i & 127;
    nf[i] = bf(Wemb[species[n] * 128 + k]) * 0.31622776601683794f;
}

// ---------- species scan ----------
__global__ void k_spscan(const int* shist, int* spoffs, int* spcursor) {
    if (threadIdx.x == 0) {
        int run = 0;
        for (int s = 0; s < 10; s++) { spoffs[s] = run; spcursor[s] = run; run += shist[s]; }
        spoffs[10] = run;
    }
}

// ---------- species sort: LDS-aggregated ----------
__global__ __launch_bounds__(256) void k_spsort(const int* species, int* spcursor, int* perm) {
    __shared__ int lcnt[10], lbase[10], lrank[10];
    int tid = threadIdx.x;
    if (tid < 10) { lcnt[tid] = 0; lrank[tid] = 0; }
    __syncthreads();
    int n = blockIdx.x * 256 + tid;
    int sp = species[n];
    atomicAdd(&lcnt[sp], 1);
    __syncthreads();
    if (tid < 10) lbase[tid] = atomicAdd(&spcursor[tid], lcnt[tid]);
    __syncthreads();
    int r = atomicAdd(&lrank[sp], 1);
    perm[lbase[sp] + r] = n;
}

// ---------- edge prep: SH + bessel + histogram ----------
__global__ __launch_bounds__(256) void k_prep_edges(const int* eidx, const void* pos,
                                                    float* esh, float* ef, int* hist,
                                                    const int* flag) {
    int e = blockIdx.x * 256 + threadIdx.x;
    int j = eidx[e], i = eidx[N_EDGES + e];
    float vx, vy, vz;
    if (*flag) {
        const u16* p = (const u16*)pos;
        vx = bf(p[j * 3 + 0]) - bf(p[i * 3 + 0]);
        vy = bf(p[j * 3 + 1]) - bf(p[i * 3 + 1]);
        vz = bf(p[j * 3 + 2]) - bf(p[i * 3 + 2]);
    } else {
        const float* p = (const float*)pos;
        vx = p[j * 3 + 0] - p[i * 3 + 0];
        vy = p[j * 3 + 1] - p[i * 3 + 1];
        vz = p[j * 3 + 2] - p[i * 3 + 2];
    }
    float r = sqrtf(vx * vx + vy * vy + vz * vz + 1e-12f);
    float rinv = 1.f / r;
    float X = vx * rinv, Y = vy * rinv, Z = vz * rinv;
    float x2 = X * X, y2 = Y * Y, z2 = Z * Z;
    const float s3 = 1.7320508075688772f, s15 = 3.872983346207417f, s5 = 2.23606797749979f;
    const float s35_8 = 2.091650066335189f, s105 = 10.246950765959598f;
    const float s21_8 = 1.6201851746019651f, s7 = 2.6457513110645907f;
    float Yh[16];
    Yh[0] = 1.f; Yh[1] = s3 * X; Yh[2] = s3 * Y; Yh[3] = s3 * Z;
    Yh[4] = s15 * X * Y; Yh[5] = s15 * Y * Z; Yh[6] = 0.5f * s5 * (3.f * z2 - 1.f);
    Yh[7] = s15 * X * Z; Yh[8] = 0.5f * s15 * (x2 - y2);
    Yh[9] = s35_8 * Y * (3.f * x2 - y2); Yh[10] = s105 * X * Y * Z;
    Yh[11] = s21_8 * Y * (5.f * z2 - 1.f); Yh[12] = 0.5f * s7 * Z * (5.f * z2 - 3.f);
    Yh[13] = s21_8 * X * (5.f * z2 - 1.f); Yh[14] = 0.5f * s105 * Z * (x2 - y2);
    Yh[15] = s35_8 * X * (x2 - 3.f * y2);
#pragma unroll
    for (int m = 0; m < 16; m++) esh[e * 16 + m] = Yh[m];

    float u = r * 0.2f;
    float fc = 0.f;
    if (u < 1.f) {
        float u2 = u * u, u4 = u2 * u2, u5 = u4 * u, u6 = u5 * u, u7 = u6 * u;
        fc = 1.f - 21.f * u5 + 35.f * u6 - 15.f * u7;
    }
    const float pref = 0.6324555320336759f; // sqrt(2/5)
#pragma unroll
    for (int nn = 1; nn <= 8; nn++)
        ef[e * 8 + nn - 1] = pref * sinf((float)nn * 3.14159265358979323846f * u) * rinv * fc;

    atomicAdd(&hist[i], 1);
}

// ---------- exclusive scan of 16384 counts ----------
__global__ __launch_bounds__(1024) void k_scan(const int* hist, int* offs, int* cursor) {
    __shared__ int part[1024];
    int t = threadIdx.x;
    int base = t * 16;
    int v[16]; int s = 0;
#pragma unroll
    for (int q = 0; q < 16; q++) { v[q] = hist[base + q]; s += v[q]; }
    part[t] = s;
    __syncthreads();
    for (int d = 1; d < 1024; d <<= 1) {
        int add = (t >= d) ? part[t - d] : 0;
        __syncthreads();
        part[t] += add;
        __syncthreads();
    }
    int run = part[t] - s; // exclusive
#pragma unroll
    for (int q = 0; q < 16; q++) { offs[base + q] = run; cursor[base + q] = run; run += v[q]; }
    if (t == 1023) offs[16384] = run;
}

// ---------- counting-sort scatter ----------
__global__ __launch_bounds__(256) void k_sort(const int* eidx, int* cursor, int* sorted) {
    int e = blockIdx.x * 256 + threadIdx.x;
    int i = eidx[N_EDGES + e];
    int p = atomicAdd(&cursor[i], 1);
    sorted[p] = e;
}

// ---------- up + sc via species-grouped MFMA GEMM ----------
__global__ __launch_bounds__(256) void k_upsc(int t, const float* nf, const int* perm,
                                              const int* spoffs, const u16* WupT,
                                              const u16* WskipT, u16* up, float* sc) {
    __shared__ u16 wu[16384];
    __shared__ u16 wsk[16384];
    int s = blockIdx.y;
    int rstart = spoffs[s] + blockIdx.x * 64;
    int rend = spoffs[s + 1];
    if (rstart >= rend) return;
    int tid = threadIdx.x;
    const u16* wg1 = WupT + (size_t)t * 16384;
    const u16* wg2 = WskipT + ((size_t)t * 10 + s) * 16384;
#pragma unroll
    for (int p = 0; p < 8; p++) {
        int slot = p * 256 + tid;
        int nt = slot >> 8, ks = (slot >> 6) & 3, ln = slot & 63;
        int nn = nt * 16 + (ln & 15), k0 = ks * 32 + (ln >> 4) * 8;
        *(uint4*)&wu[slot * 8]  = *(const uint4*)&wg1[nn * 128 + k0];
        *(uint4*)&wsk[slot * 8] = *(const uint4*)&wg2[nn * 128 + k0];
    }
    __syncthreads();

    int wave = tid >> 6, lane = tid & 63;
    int m16 = lane & 15, quad = lane >> 4;
    int arow = rstart + wave * 16 + m16;
    int anode = perm[arow < rend ? arow : rstart];
    short8 afr[4];
#pragma unroll
    for (int ks = 0; ks < 4; ks++) {
        const float* ap = nf + (size_t)anode * 128 + ks * 32 + quad * 8;
        short8 v;
#pragma unroll
        for (int q = 0; q < 8; q++) v[q] = (short)fb(ap[q]);
        afr[ks] = v;
    }

    float4v accU[8], accS[8];
#pragma unroll
    for (int nt = 0; nt < 8; nt++) {
        accU[nt] = (float4v){0.f, 0.f, 0.f, 0.f};
        accS[nt] = (float4v){0.f, 0.f, 0.f, 0.f};
#pragma unroll
        for (int ks = 0; ks < 4; ks++) {
            short8 b1 = *(const short8*)&wu[((nt * 4 + ks) * 64 + lane) * 8];
            short8 b2 = *(const short8*)&wsk[((nt * 4 + ks) * 64 + lane) * 8];
            accU[nt] = __builtin_amdgcn_mfma_f32_16x16x32_bf16(afr[ks], b1, accU[nt], 0, 0, 0);
            accS[nt] = __builtin_amdgcn_mfma_f32_16x16x32_bf16(afr[ks], b2, accS[nt], 0, 0, 0);
        }
    }

    int crow0 = rstart + wave * 16 + quad * 4;
    int cnode[4]; int cvalid[4];
#pragma unroll
    for (int r = 0; r < 4; r++) {
        int rr = crow0 + r;
        cvalid[r] = rr < rend;
        cnode[r] = perm[cvalid[r] ? rr : rstart];
    }
#pragma unroll
    for (int nt = 0; nt < 8; nt++) {
        int col = nt * 16 + m16;
#pragma unroll
        for (int r = 0; r < 4; r++) {
            if (cvalid[r]) {
                up[(size_t)cnode[r] * 128 + col] = fb(accU[nt][r] * 0.08838834764831845f);
                sc[(size_t)cnode[r] * 128 + col] = accS[nt][r] * 0.027950849718747373f;
            }
        }
    }
}

// ---------- radial MLP via MFMA (r12 version, proven 46.3 us) ----------
#define HS 68
__global__ __launch_bounds__(64) void k_radial(int t, const float* ef, const u16* Wr0,
                                               const u16* Wr1T, const u16* Wr2T,
                                               const u16* Wr3T, u16* tpw) {
    __shared__ u16 w0s[512];
    __shared__ u16 hbuf[2176];   // h0 [0,1088) | h1 [1088,2176); L3 staging aliases all
    int tid = threadIdx.x;
    const u16* w0p = Wr0 + t * 512;
    *(uint4*)&w0s[tid * 8] = *(const uint4*)&w0p[tid * 8];
    __syncthreads();

    int lane = tid;
    int m16 = lane & 15, quad = lane >> 4;
    int E0 = blockIdx.x * 16;
    u16* h0 = &hbuf[0];
    u16* h1 = &hbuf[1088];

    // ---- L0 (VALU, K=8) ----
    float efv[8];
    {
        const float* ep = ef + (size_t)(E0 + m16) * 8;
        float4 e0 = *(const float4*)ep, e1 = *(const float4*)(ep + 4);
        efv[0] = e0.x; efv[1] = e0.y; efv[2] = e0.z; efv[3] = e0.w;
        efv[4] = e1.x; efv[5] = e1.y; efv[6] = e1.z; efv[7] = e1.w;
    }
#pragma unroll
    for (int o = 0; o < 16; o++) {
        int oc = quad * 16 + o;
        float a = 0.f;
#pragma unroll
        for (int b = 0; b < 8; b++) a += efv[b] * bf(w0s[b * 64 + oc]);
        h0[m16 * HS + oc] = fb(silu_f(a * 0.35355339059327373f));
    }
    __syncthreads();

    // ---- L1 (MFMA 16x16x32, K=64, N=64) ----
    const u16* w1p = Wr1T + t * 4096;
    short8 afr[2];
    afr[0] = *(const short8*)&h0[m16 * HS + quad * 8];
    afr[1] = *(const short8*)&h0[m16 * HS + 32 + quad * 8];
    {
        float4v acc[4];
#pragma unroll
        for (int nt = 0; nt < 4; nt++) {
            acc[nt] = (float4v){0.f, 0.f, 0.f, 0.f};
#pragma unroll
            for (int ks = 0; ks < 2; ks++) {
                short8 bfr = *(const short8*)&w1p[(nt * 16 + m16) * 64 + ks * 32 + quad * 8];
                acc[nt] = __builtin_amdgcn_mfma_f32_16x16x32_bf16(afr[ks], bfr, acc[nt], 0, 0, 0);
            }
        }
#pragma unroll
        for (int nt = 0; nt < 4; nt++)
#pragma unroll
            for (int r = 0; r < 4; r++)
                h1[(quad * 4 + r) * HS + nt * 16 + m16] = fb(silu_f(acc[nt][r] * 0.125f));
    }
    __syncthreads();

    // ---- L2 (MFMA, K=64, N=64) ----
    const u16* w2p = Wr2T + t * 4096;
    afr[0] = *(const short8*)&h1[m16 * HS + quad * 8];
    afr[1] = *(const short8*)&h1[m16 * HS + 32 + quad * 8];
    {
        float4v acc[4];
#pragma unroll
        for (int nt = 0; nt < 4; nt++) {
            acc[nt] = (float4v){0.f, 0.f, 0.f, 0.f};
#pragma unroll
            for (int ks = 0; ks < 2; ks++) {
                short8 bfr = *(const short8*)&w2p[(nt * 16 + m16) * 64 + ks * 32 + quad * 8];
                acc[nt] = __builtin_amdgcn_mfma_f32_16x16x32_bf16(afr[ks], bfr, acc[nt], 0, 0, 0);
            }
        }
#pragma unroll
        for (int nt = 0; nt < 4; nt++)
#pragma unroll
            for (int r = 0; r < 4; r++)
                h0[(quad * 4 + r) * HS + nt * 16 + m16] = fb(silu_f(acc[nt][r] * 0.125f));
    }
    __syncthreads();

    // ---- L3 (MFMA, K=64, N=512), chunked 4x128; staging aliases hbuf ----
    const u16* w3p = Wr3T + t * 32768;
    afr[0] = *(const short8*)&h0[m16 * HS + quad * 8];
    afr[1] = *(const short8*)&h0[m16 * HS + 32 + quad * 8];
    u16* stw = &hbuf[0];
    for (int cc = 0; cc < 4; cc++) {
#pragma unroll
        for (int nt8 = 0; nt8 < 8; nt8++) {
            int nt = cc * 8 + nt8;
            float4v a3 = (float4v){0.f, 0.f, 0.f, 0.f};
#pragma unroll
            for (int ks = 0; ks < 2; ks++) {
                short8 bfr = *(const short8*)&w3p[(nt * 16 + m16) * 64 + ks * 32 + quad * 8];
                a3 = __builtin_amdgcn_mfma_f32_16x16x32_bf16(afr[ks], bfr, a3, 0, 0, 0);
            }
#pragma unroll
            for (int r = 0; r < 4; r++)
                stw[(quad * 4 + r) * 136 + nt8 * 16 + m16] = fb(a3[r] * 0.125f);
        }
        __syncthreads();
#pragma unroll
        for (int st = 0; st < 4; st++) {
            int edge = st * 4 + quad;
            uint4 v = *(const uint4*)&stw[edge * 136 + m16 * 8];
            *(uint4*)&tpw[(size_t)(E0 + edge) * 512 + cc * 128 + m16 * 8] = v;
        }
        __syncthreads();
    }
}
#undef HS

// ---------- message accumulation -> l-grouped global msg (bf16) ----------
__global__ __launch_bounds__(256) void k_msg(const int* offs, const int* sorted,
                                             const int* eidx, const float* esh,
                                             const u16* up, const u16* tpw, u16* msgA) {
    const int LM[16] = {0,1,1,1,2,2,2,2,2,3,3,3,3,3,3,3};
    int tid = threadIdx.x;
    int nsub = tid >> 5;
    int kq = tid & 31;
    int k4 = kq * 4;
    int n = blockIdx.x * 8 + nsub;

    float acc[16][4];
#pragma unroll
    for (int m = 0; m < 16; m++)
#pragma unroll
        for (int q = 0; q < 4; q++) acc[m][q] = 0.f;
    int s = offs[n], e1 = offs[n + 1];
    for (int idx = s; idx < e1; idx++) {
        int e = sorted[idx];
        int j = eidx[e];
        ushort4 uu = *(const ushort4*)(up + (size_t)j * 128 + k4);
        float u0 = bf(uu.x), u1 = bf(uu.y), u2 = bf(uu.z), u3 = bf(uu.w);
        float4 sA = *(const float4*)(esh + (size_t)e * 16);
        float4 sB = *(const float4*)(esh + (size_t)e * 16 + 4);
        float4 sC = *(const float4*)(esh + (size_t)e * 16 + 8);
        float4 sD = *(const float4*)(esh + (size_t)e * 16 + 12);
        float sh[16] = {sA.x, sA.y, sA.z, sA.w, sB.x, sB.y, sB.z, sB.w,
                        sC.x, sC.y, sC.z, sC.w, sD.x, sD.y, sD.z, sD.w};
        float p[4][4];
#pragma unroll
        for (int l = 0; l < 4; l++) {
            ushort4 tp = *(const ushort4*)(tpw + (size_t)e * 512 + l * 128 + k4);
            p[l][0] = u0 * bf(tp.x); p[l][1] = u1 * bf(tp.y);
            p[l][2] = u2 * bf(tp.z); p[l][3] = u3 * bf(tp.w);
        }
#pragma unroll
        for (int m = 0; m < 16; m++) {
            int l = LM[m];
            acc[m][0] += sh[m] * p[l][0]; acc[m][1] += sh[m] * p[l][1];
            acc[m][2] += sh[m] * p[l][2]; acc[m][3] += sh[m] * p[l][3];
        }
    }
#pragma unroll
    for (int m = 0; m < 16; m++) {
        int row = RBc[m] + n * RSc[m];
        ushort4 o;
        o.x = fb(acc[m][0] * 0.1f); o.y = fb(acc[m][1] * 0.1f);
        o.z = fb(acc[m][2] * 0.1f); o.w = fb(acc[m][3] * 0.1f);
        *(ushort4*)(msgA + (size_t)row * 128 + k4) = o;
    }
}

// ---------- FUSED A-GEMM + invariants + product -> bvec (v2: no spill) ----------
// 4 waves/block = 2 node-groups x 2 channel-halves. Each wave: 16 nodes x 64
// channels (nt = nth*4..nth*4+3). Accumulators A0[4][4]+inv2[4][4][4] = 80 VGPR.
// A never touches HBM; bvec written in epilogue.
__global__ __launch_bounds__(256) void k_gemmAb(int t, const u16* msgA, const u16* WlinT,
                                                const int* species,
                                                const u16* Wp1, const u16* Wp2, const u16* Wp3,
                                                u16* bvec) {
    __shared__ u16 wfr[16384];
    int tid = threadIdx.x;
    int wave = tid >> 6, lane = tid & 63;
    int m16 = lane & 15, quad = lane >> 4;
    int grp = wave >> 1;          // node group within block (0/1)
    int nth = wave & 1;           // channel half: nt = nth*4 + ntl
    int n0w = blockIdx.x * 32 + grp * 16;
    const float sAc = 0.08838834764831845f;

    float A0[4][4];
    float inv2[4][4][4];
#pragma unroll
    for (int l = 0; l < 4; l++)
#pragma unroll
        for (int ntl = 0; ntl < 4; ntl++)
#pragma unroll
            for (int r = 0; r < 4; r++) inv2[l][ntl][r] = 0.f;

    const int ms_[4] = {0, 1, 4, 9}, me_[4] = {1, 4, 9, 16};
#pragma unroll
    for (int l = 0; l < 4; l++) {
        __syncthreads();   // protect previous l's wfr reads
        const u16* wg = WlinT + ((size_t)t * 4 + l) * 16384;
#pragma unroll
        for (int p = 0; p < 8; p++) {
            int slot = p * 256 + tid;
            int nt = slot >> 8, ks = (slot >> 6) & 3, ln = slot & 63;
            int nn = nt * 16 + (ln & 15), k0 = ks * 32 + (ln >> 4) * 8;
            *(uint4*)&wfr[slot * 8] = *(const uint4*)&wg[nn * 128 + k0];
        }
        __syncthreads();
#pragma unroll
        for (int m = ms_[l]; m < me_[l]; m++) {
            int rowa = RBc[m] + (n0w + m16) * RSc[m];
            const u16* ap = msgA + (size_t)rowa * 128 + quad * 8;
            short8 afr[4];
#pragma unroll
            for (int ks = 0; ks < 4; ks++) afr[ks] = *(const short8*)(ap + ks * 32);
#pragma unroll
            for (int ntl = 0; ntl < 4; ntl++) {
                int nt = nth * 4 + ntl;
                float4v acc = (float4v){0.f, 0.f, 0.f, 0.f};
#pragma unroll
                for (int ks = 0; ks < 4; ks++) {
                    short8 bfr = *(const short8*)&wfr[((nt * 4 + ks) * 64 + lane) * 8];
                    acc = __builtin_amdgcn_mfma_f32_16x16x32_bf16(afr[ks], bfr, acc, 0, 0, 0);
                }
#pragma unroll
                for (int r = 0; r < 4; r++) {
                    float a = acc[r] * sAc;
                    if (m == 0) A0[ntl][r] = a;
                    inv2[l][ntl][r] += a * a;
                }
            }
        }
    }

    // ---- epilogue: b = w1*A0 + w2.inv2 + (w3.inv2)*A0 -> bvec ----
#pragma unroll
    for (int r = 0; r < 4; r++) {
        int n = n0w + quad * 4 + r;
        int sp = species[n];
        const u16* p1 = Wp1 + ((size_t)t * 10 + sp) * 128;
        const u16* p2 = Wp2 + ((size_t)t * 10 + sp) * 4 * 128;
        const u16* p3 = Wp3 + ((size_t)t * 10 + sp) * 4 * 128;
#pragma unroll
        for (int ntl = 0; ntl < 4; ntl++) {
            int ch = (nth * 4 + ntl) * 16 + m16;
            float w1 = bf(p1[ch]);
            float s2 = 0.f, s3 = 0.f;
#pragma unroll
            for (int l = 0; l < 4; l++) {
                s2 += bf(p2[l * 128 + ch]) * inv2[l][ntl][r];
                s3 += bf(p3[l * 128 + ch]) * inv2[l][ntl][r];
            }
            bvec[(size_t)n * 128 + ch] = fb(w1 * A0[ntl][r] + s2 + s3 * A0[ntl][r]);
        }
    }
}

// ---------- nf = bvec @ WplT / sqrt(128) + sc ----------
__global__ __launch_bounds__(256) void k_gemm_nf(int t, const u16* bvec, const u16* WplT,
                                                 const float* sc, float* nf) {
    __shared__ u16 wfr[16384];
    int rb0 = blockIdx.x * 64;
    int tid = threadIdx.x;
    const u16* wg = WplT + (size_t)t * 16384;
#pragma unroll
    for (int p = 0; p < 8; p++) {
        int slot = p * 256 + tid;
        int nt = slot >> 8, ks = (slot >> 6) & 3, ln = slot & 63;
        int nn = nt * 16 + (ln & 15), k0 = ks * 32 + (ln >> 4) * 8;
        *(uint4*)&wfr[slot * 8] = *(const uint4*)&wg[nn * 128 + k0];
    }
    __syncthreads();

    int wave = tid >> 6, lane = tid & 63;
    int m16 = lane & 15, quad = lane >> 4;
    int rowa = rb0 + wave * 16 + m16;
    const u16* ap = bvec + (size_t)rowa * 128 + quad * 8;
    short8 afr[4];
#pragma unroll
    for (int ks = 0; ks < 4; ks++) afr[ks] = *(const short8*)(ap + ks * 32);

    float4v acc[8];
#pragma unroll
    for (int nt = 0; nt < 8; nt++) acc[nt] = (float4v){0.f, 0.f, 0.f, 0.f};
#pragma unroll
    for (int nt = 0; nt < 8; nt++)
#pragma unroll
        for (int ks = 0; ks < 4; ks++) {
            short8 bfr = *(const short8*)&wfr[((nt * 4 + ks) * 64 + lane) * 8];
            acc[nt] = __builtin_amdgcn_mfma_f32_16x16x32_bf16(afr[ks], bfr, acc[nt], 0, 0, 0);
        }

    const float sAc = 0.08838834764831845f;
    int rowc = rb0 + wave * 16 + quad * 4;
#pragma unroll
    for (int nt = 0; nt < 8; nt++) {
        int col = nt * 16 + m16;
#pragma unroll
        for (int r = 0; r < 4; r++) {
            size_t idx = (size_t)(rowc + r) * 128 + col;
            nf[idx] = acc[nt][r] * sAc + sc[idx];
        }
    }
}

// ---------- graph readout: 8 nodes/block, register segment-sum + atomic flush ----------
__global__ __launch_bounds__(128) void k_reduce(const float* nf, const int* batch,
                                                float* env, float* cnt) {
    int k = threadIdx.x;
    int n0 = blockIdx.x * 8;
    float run = 0.f;
    int c = 0;
    int gp = batch[n0];
    for (int nn = 0; nn < 8; nn++) {
        int n = n0 + nn;
        int g = batch[n];
        if (g != gp) {
            atomicAdd(&env[gp * 128 + k], run);
            if (k == 0) atomicAdd(&cnt[gp], (float)c);
            run = 0.f; c = 0; gp = g;
        }
        run += nf[(size_t)n * 128 + k];
        c++;
    }
    atomicAdd(&env[gp * 128 + k], run);
    if (k == 0) atomicAdd(&cnt[gp], (float)c);
}

// ---------- final: output float32 ----------
__global__ void k_final(const float* env, const float* cnt, float* out) {
    int i = blockIdx.x * 256 + threadIdx.x;
    if (i < N_GRAPHS * 128) out[i] = env[i] / fmaxf(cnt[i >> 7], 1.f);
}

// ---------- launch ----------
extern "C" void kernel_launch(void* const* d_in, const int* in_sizes, int n_in,
                              void* d_out, int out_size, void* d_ws, size_t ws_size,
                              hipStream_t stream) {
    (void)in_sizes; (void)n_in; (void)out_size; (void)ws_size;
    const void* x    = d_in[0];
    const void* pos  = d_in[1];
    const int* eidx  = (const int*)d_in[14];
    const int* batch = (const int*)d_in[15];

    char* base = (char*)d_ws;
    size_t cur = 0;
    auto alloc = [&](size_t bytes) -> void* {
        void* p = base + cur;
        cur = (cur + bytes + 255) & ~(size_t)255;
        return p;
    };
    int*   flag    = (int*)alloc(4);
    u16*   cvt     = (u16*)alloc((size_t)631552 * 2);
    int*   species = (int*)alloc((size_t)N_NODES * 4);
    int*   shist   = (int*)alloc(64);
    int*   spoffs  = (int*)alloc(64);
    int*   spcursor= (int*)alloc(64);
    int*   perm    = (int*)alloc((size_t)N_NODES * 4);
    int*   hist    = (int*)alloc((size_t)N_NODES * 4);
    int*   offs    = (int*)alloc((size_t)(N_NODES + 1) * 4);
    int*   cursor  = (int*)alloc((size_t)N_NODES * 4);
    int*   sorted  = (int*)alloc((size_t)N_EDGES * 4);
    float* env     = (float*)alloc((size_t)N_GRAPHS * 128 * 4);
    float* cnt     = (float*)alloc((size_t)N_GRAPHS * 4);
    float* nf      = (float*)alloc((size_t)N_NODES * 128 * 4);
    u16*   up      = (u16*)alloc((size_t)N_NODES * 128 * 2);
    u16*   bvec    = (u16*)alloc((size_t)N_NODES * 128 * 2);
    float* sc      = (float*)alloc((size_t)N_NODES * 128 * 4);
    float* ef      = (float*)alloc((size_t)N_EDGES * 8 * 4);
    float* esh     = (float*)alloc((size_t)N_EDGES * 16 * 4);
    u16*   tpw     = (u16*)alloc((size_t)N_EDGES * 512 * 2);
    u16*   msgA    = (u16*)alloc((size_t)262144 * 128 * 2);

    static const int cn[12] = {1280, 32768, 1024, 8192, 8192, 65536,
                               131072, 327680, 2560, 10240, 10240, 32768};
    CvtArgs ca;
    size_t off[13]; off[0] = 0;
    for (int q = 0; q < 12; q++) { ca.src[q] = d_in[2 + q]; ca.n[q] = cn[q]; off[q + 1] = off[q] + cn[q]; }
    u16* cWemb  = cvt + off[0];
    u16* cWupT  = cvt + off[1];
    u16* cWr0   = cvt + off[2];
    u16* cWr1T  = cvt + off[3];
    u16* cWr2T  = cvt + off[4];
    u16* cWr3T  = cvt + off[5];
    u16* cWlinT = cvt + off[6];
    u16* cWskipT= cvt + off[7];
    u16* cWp1   = cvt + off[8];
    u16* cWp2   = cvt + off[9];
    u16* cWp3   = cvt + off[10];
    u16* cWplT  = cvt + off[11];

    k_detect<<<1, 256, 0, stream>>>(x, flag);
    k_convert<<<256, 256, 0, stream>>>(ca, cvt, flag);
    k_zero<<<64, 256, 0, stream>>>((float*)hist, N_NODES);
    k_zero<<<1, 64, 0, stream>>>((float*)shist, 16);
    k_zero<<<32, 256, 0, stream>>>(env, N_GRAPHS * 128);
    k_zero<<<1, 256, 0, stream>>>(cnt, N_GRAPHS);
    k_species<<<N_NODES / 256, 256, 0, stream>>>(x, species, shist, flag);
    k_embed<<<N_NODES * 128 / 256, 256, 0, stream>>>(species, cWemb, nf);
    k_spscan<<<1, 64, 0, stream>>>(shist, spoffs, spcursor);
    k_spsort<<<N_NODES / 256, 256, 0, stream>>>(species, spcursor, perm);
    k_prep_edges<<<N_EDGES / 256, 256, 0, stream>>>(eidx, pos, esh, ef, hist, flag);
    k_scan<<<1, 1024, 0, stream>>>(hist, offs, cursor);
    k_sort<<<N_EDGES / 256, 256, 0, stream>>>(eidx, cursor, sorted);

    for (int t = 0; t < 2; t++) {
        k_upsc<<<dim3(256, 10), 256, 0, stream>>>(t, nf, perm, spoffs, cWupT, cWskipT, up, sc);
        k_radial<<<N_EDGES / 16, 64, 0, stream>>>(t, ef, cWr0, cWr1T, cWr2T, cWr3T, tpw);
        k_msg<<<N_NODES / 8, 256, 0, stream>>>(offs, sorted, eidx, esh, up, tpw, msgA);
        k_gemmAb<<<N_NODES / 32, 256, 0, stream>>>(t, msgA, cWlinT, species,
                                                   cWp1, cWp2, cWp3, bvec);
        k_gemm_nf<<<N_NODES / 64, 256, 0, stream>>>(t, bvec, cWplT, sc, nf);
    }
    k_reduce<<<N_NODES / 8, 128, 0, stream>>>(nf, batch, env, cnt);
    k_final<<<32, 256, 0, stream>>>(env, cnt, (float*)d_out);
}

// Round 16
// 447.770 us; speedup vs baseline: 1.0617x; 1.0028x over previous
//
#include <hip/hip_runtime.h>

typedef unsigned short u16;
typedef unsigned int   u32;
typedef __attribute__((ext_vector_type(8))) short short8;
typedef __attribute__((ext_vector_type(4))) float float4v;

#define N_NODES  16384
#define N_EDGES  65536
#define N_GRAPHS 64

// ---------- helpers ----------
__device__ __forceinline__ float bf(u16 u) { return __uint_as_float(((u32)u) << 16); }
__device__ __forceinline__ u16 fb(float f) {
    u32 b = __float_as_uint(f);
    b += 0x7FFFu + ((b >> 16) & 1u);   // round-to-nearest-even
    return (u16)(b >> 16);
}
__device__ __forceinline__ float silu_f(float x) { return x / (1.f + __expf(-x)); }

// l-grouped msg row layout: row = RB[m] + n*RS[m]
__device__ __constant__ int RBc[16] = {0, 16384,16385,16386, 65536,65537,65538,65539,65540,
                                       147456,147457,147458,147459,147460,147461,147462};
__device__ __constant__ int RSc[16] = {1,3,3,3,5,5,5,5,5,7,7,7,7,7,7,7};

// ---------- zero ----------
__global__ void k_zero(float* p, int n) {
    int i = blockIdx.x * 256 + threadIdx.x;
    if (i < n) p[i] = 0.f;
}

// ---------- input dtype detector (flag=1 => bf16 inputs; f32 gives flag=0) ----------
__global__ void k_detect(const void* x, int* flag) {
    __shared__ int f;
    if (threadIdx.x == 0) f = 0;
    __syncthreads();
    const u16* p = (const u16*)x;
    for (int i = threadIdx.x; i < 4096; i += 256)
        if (p[i] == 0x3F80u && (i & 1) == 0) f = 1;
    __syncthreads();
    if (threadIdx.x == 0) *flag = f;
}

// ---------- convert 12 weight arrays to canonical bf16 copies ----------
struct CvtArgs { const void* src[12]; int n[12]; };
__global__ void k_convert(CvtArgs a, u16* dst, const int* flag) {
    int fl = *flag;
    size_t base = 0;
    int stride = gridDim.x * 256;
    for (int q = 0; q < 12; q++) {
        int n = a.n[q];
        for (int i = blockIdx.x * 256 + threadIdx.x; i < n; i += stride) {
            u16 v;
            if (fl) v = ((const u16*)a.src[q])[i];
            else    v = fb(((const float*)a.src[q])[i]);
            if (q == 6) {
                int slab = i >> 14, rem = i & 16383, kk = rem >> 7, nn = rem & 127;
                dst[base + slab * 16384 + nn * 128 + kk] = v;
            } else if (q == 3 || q == 4) {
                int tq = i >> 12, rem = i & 4095, kk = rem >> 6, nn = rem & 63;
                dst[base + tq * 4096 + nn * 64 + kk] = v;
            } else if (q == 5) {
                int tq = i >> 15, rem = i & 32767, kk = rem >> 9, nn = rem & 511;
                dst[base + tq * 32768 + nn * 64 + kk] = v;
            } else if (q == 1 || q == 11) {
                int tq = i >> 14, rem = i & 16383, kk = rem >> 7, k = rem & 127;
                dst[base + tq * 16384 + k * 128 + kk] = v;
            } else if (q == 7) {
                int tq = i >= 163840 ? 1 : 0, rem = i - tq * 163840;
                int sp = rem >> 14, r2 = rem & 16383, kk = r2 >> 7, k = r2 & 127;
                dst[base + ((size_t)tq * 10 + sp) * 16384 + k * 128 + kk] = v;
            } else {
                dst[base + i] = v;
            }
        }
        base += n;
    }
}

// ---------- species + LDS-aggregated histogram ----------
__global__ __launch_bounds__(256) void k_species(const void* x, int* species, int* shist,
                                                 const int* flag) {
    __shared__ int lh[10];
    int tid = threadIdx.x;
    if (tid < 10) lh[tid] = 0;
    __syncthreads();
    int n = blockIdx.x * 256 + tid;
    int sp = 0;
    if (*flag) {
        const u16* xp = (const u16*)x + (size_t)n * 10;
        for (int z = 0; z < 10; z++)
            if (bf(xp[z]) > 0.5f) { sp = z; break; }
    } else {
        const float* xp = (const float*)x + (size_t)n * 10;
        for (int z = 0; z < 10; z++)
            if (xp[z] > 0.5f) { sp = z; break; }
    }
    species[n] = sp;
    atomicAdd(&lh[sp], 1);
    __syncthreads();
    if (tid < 10) atomicAdd(&shist[tid], lh[tid]);
}

// ---------- embedding fill ----------
__global__ __launch_bounds__(256) void k_embed(const int* species, const u16* Wemb, float* nf) {
    int i = blockIdx.x * 256 + threadIdx.x;
    int n = i >> 7, k = i & 127;
    nf[i] = bf(Wemb[species[n] * 128 + k]) * 0.31622776601683794f;
}

// ---------- species scan ----------
__global__ void k_spscan(const int* shist, int* spoffs, int* spcursor) {
    if (threadIdx.x == 0) {
        int run = 0;
        for (int s = 0; s < 10; s++) { spoffs[s] = run; spcursor[s] = run; run += shist[s]; }
        spoffs[10] = run;
    }
}

// ---------- species sort: LDS-aggregated ----------
__global__ __launch_bounds__(256) void k_spsort(const int* species, int* spcursor, int* perm) {
    __shared__ int lcnt[10], lbase[10], lrank[10];
    int tid = threadIdx.x;
    if (tid < 10) { lcnt[tid] = 0; lrank[tid] = 0; }
    __syncthreads();
    int n = blockIdx.x * 256 + tid;
    int sp = species[n];
    atomicAdd(&lcnt[sp], 1);
    __syncthreads();
    if (tid < 10) lbase[tid] = atomicAdd(&spcursor[tid], lcnt[tid]);
    __syncthreads();
    int r = atomicAdd(&lrank[sp], 1);
    perm[lbase[sp] + r] = n;
}

// ---------- edge prep: SH + bessel + histogram ----------
__global__ __launch_bounds__(256) void k_prep_edges(const int* eidx, const void* pos,
                                                    float* esh, float* ef, int* hist,
                                                    const int* flag) {
    int e = blockIdx.x * 256 + threadIdx.x;
    int j = eidx[e], i = eidx[N_EDGES + e];
    float vx, vy, vz;
    if (*flag) {
        const u16* p = (const u16*)pos;
        vx = bf(p[j * 3 + 0]) - bf(p[i * 3 + 0]);
        vy = bf(p[j * 3 + 1]) - bf(p[i * 3 + 1]);
        vz = bf(p[j * 3 + 2]) - bf(p[i * 3 + 2]);
    } else {
        const float* p = (const float*)pos;
        vx = p[j * 3 + 0] - p[i * 3 + 0];
        vy = p[j * 3 + 1] - p[i * 3 + 1];
        vz = p[j * 3 + 2] - p[i * 3 + 2];
    }
    float r = sqrtf(vx * vx + vy * vy + vz * vz + 1e-12f);
    float rinv = 1.f / r;
    float X = vx * rinv, Y = vy * rinv, Z = vz * rinv;
    float x2 = X * X, y2 = Y * Y, z2 = Z * Z;
    const float s3 = 1.7320508075688772f, s15 = 3.872983346207417f, s5 = 2.23606797749979f;
    const float s35_8 = 2.091650066335189f, s105 = 10.246950765959598f;
    const float s21_8 = 1.6201851746019651f, s7 = 2.6457513110645907f;
    float Yh[16];
    Yh[0] = 1.f; Yh[1] = s3 * X; Yh[2] = s3 * Y; Yh[3] = s3 * Z;
    Yh[4] = s15 * X * Y; Yh[5] = s15 * Y * Z; Yh[6] = 0.5f * s5 * (3.f * z2 - 1.f);
    Yh[7] = s15 * X * Z; Yh[8] = 0.5f * s15 * (x2 - y2);
    Yh[9] = s35_8 * Y * (3.f * x2 - y2); Yh[10] = s105 * X * Y * Z;
    Yh[11] = s21_8 * Y * (5.f * z2 - 1.f); Yh[12] = 0.5f * s7 * Z * (5.f * z2 - 3.f);
    Yh[13] = s21_8 * X * (5.f * z2 - 1.f); Yh[14] = 0.5f * s105 * Z * (x2 - y2);
    Yh[15] = s35_8 * X * (x2 - 3.f * y2);
#pragma unroll
    for (int m = 0; m < 16; m++) esh[e * 16 + m] = Yh[m];

    float u = r * 0.2f;
    float fc = 0.f;
    if (u < 1.f) {
        float u2 = u * u, u4 = u2 * u2, u5 = u4 * u, u6 = u5 * u, u7 = u6 * u;
        fc = 1.f - 21.f * u5 + 35.f * u6 - 15.f * u7;
    }
    const float pref = 0.6324555320336759f; // sqrt(2/5)
#pragma unroll
    for (int nn = 1; nn <= 8; nn++)
        ef[e * 8 + nn - 1] = pref * sinf((float)nn * 3.14159265358979323846f * u) * rinv * fc;

    atomicAdd(&hist[i], 1);
}

// ---------- exclusive scan of 16384 counts ----------
__global__ __launch_bounds__(1024) void k_scan(const int* hist, int* offs, int* cursor) {
    __shared__ int part[1024];
    int t = threadIdx.x;
    int base = t * 16;
    int v[16]; int s = 0;
#pragma unroll
    for (int q = 0; q < 16; q++) { v[q] = hist[base + q]; s += v[q]; }
    part[t] = s;
    __syncthreads();
    for (int d = 1; d < 1024; d <<= 1) {
        int add = (t >= d) ? part[t - d] : 0;
        __syncthreads();
        part[t] += add;
        __syncthreads();
    }
    int run = part[t] - s; // exclusive
#pragma unroll
    for (int q = 0; q < 16; q++) { offs[base + q] = run; cursor[base + q] = run; run += v[q]; }
    if (t == 1023) offs[16384] = run;
}

// ---------- counting-sort scatter ----------
__global__ __launch_bounds__(256) void k_sort(const int* eidx, int* cursor, int* sorted) {
    int e = blockIdx.x * 256 + threadIdx.x;
    int i = eidx[N_EDGES + e];
    int p = atomicAdd(&cursor[i], 1);
    sorted[p] = e;
}

// ---------- up + sc via species-grouped MFMA GEMM ----------
__global__ __launch_bounds__(256) void k_upsc(int t, const float* nf, const int* perm,
                                              const int* spoffs, const u16* WupT,
                                              const u16* WskipT, u16* up, float* sc) {
    __shared__ u16 wu[16384];
    __shared__ u16 wsk[16384];
    int s = blockIdx.y;
    int rstart = spoffs[s] + blockIdx.x * 64;
    int rend = spoffs[s + 1];
    if (rstart >= rend) return;
    int tid = threadIdx.x;
    const u16* wg1 = WupT + (size_t)t * 16384;
    const u16* wg2 = WskipT + ((size_t)t * 10 + s) * 16384;
#pragma unroll
    for (int p = 0; p < 8; p++) {
        int slot = p * 256 + tid;
        int nt = slot >> 8, ks = (slot >> 6) & 3, ln = slot & 63;
        int nn = nt * 16 + (ln & 15), k0 = ks * 32 + (ln >> 4) * 8;
        *(uint4*)&wu[slot * 8]  = *(const uint4*)&wg1[nn * 128 + k0];
        *(uint4*)&wsk[slot * 8] = *(const uint4*)&wg2[nn * 128 + k0];
    }
    __syncthreads();

    int wave = tid >> 6, lane = tid & 63;
    int m16 = lane & 15, quad = lane >> 4;
    int arow = rstart + wave * 16 + m16;
    int anode = perm[arow < rend ? arow : rstart];
    short8 afr[4];
#pragma unroll
    for (int ks = 0; ks < 4; ks++) {
        const float* ap = nf + (size_t)anode * 128 + ks * 32 + quad * 8;
        short8 v;
#pragma unroll
        for (int q = 0; q < 8; q++) v[q] = (short)fb(ap[q]);
        afr[ks] = v;
    }

    float4v accU[8], accS[8];
#pragma unroll
    for (int nt = 0; nt < 8; nt++) {
        accU[nt] = (float4v){0.f, 0.f, 0.f, 0.f};
        accS[nt] = (float4v){0.f, 0.f, 0.f, 0.f};
#pragma unroll
        for (int ks = 0; ks < 4; ks++) {
            short8 b1 = *(const short8*)&wu[((nt * 4 + ks) * 64 + lane) * 8];
            short8 b2 = *(const short8*)&wsk[((nt * 4 + ks) * 64 + lane) * 8];
            accU[nt] = __builtin_amdgcn_mfma_f32_16x16x32_bf16(afr[ks], b1, accU[nt], 0, 0, 0);
            accS[nt] = __builtin_amdgcn_mfma_f32_16x16x32_bf16(afr[ks], b2, accS[nt], 0, 0, 0);
        }
    }

    int crow0 = rstart + wave * 16 + quad * 4;
    int cnode[4]; int cvalid[4];
#pragma unroll
    for (int r = 0; r < 4; r++) {
        int rr = crow0 + r;
        cvalid[r] = rr < rend;
        cnode[r] = perm[cvalid[r] ? rr : rstart];
    }
#pragma unroll
    for (int nt = 0; nt < 8; nt++) {
        int col = nt * 16 + m16;
#pragma unroll
        for (int r = 0; r < 4; r++) {
            if (cvalid[r]) {
                up[(size_t)cnode[r] * 128 + col] = fb(accU[nt][r] * 0.08838834764831845f);
                sc[(size_t)cnode[r] * 128 + col] = accS[nt][r] * 0.027950849718747373f;
            }
        }
    }
}

// ---------- radial MLP via MFMA (r12 structure; tpw now L-MAJOR for 1KB stores) ----------
// tpw layout: tpw[(l*N_EDGES + e)*128 + k]. Final store: lanes (quad=edge, m16=k8)
// cover 4 consecutive edges x 256B = ONE contiguous 1KB segment per instruction.
#define HS 68
__global__ __launch_bounds__(64) void k_radial(int t, const float* ef, const u16* Wr0,
                                               const u16* Wr1T, const u16* Wr2T,
                                               const u16* Wr3T, u16* tpw) {
    __shared__ u16 w0s[512];
    __shared__ u16 hbuf[2176];   // h0 [0,1088) | h1 [1088,2176); L3 staging aliases all
    int tid = threadIdx.x;
    const u16* w0p = Wr0 + t * 512;
    *(uint4*)&w0s[tid * 8] = *(const uint4*)&w0p[tid * 8];
    __syncthreads();

    int lane = tid;
    int m16 = lane & 15, quad = lane >> 4;
    int E0 = blockIdx.x * 16;
    u16* h0 = &hbuf[0];
    u16* h1 = &hbuf[1088];

    // ---- L0 (VALU, K=8) ----
    float efv[8];
    {
        const float* ep = ef + (size_t)(E0 + m16) * 8;
        float4 e0 = *(const float4*)ep, e1 = *(const float4*)(ep + 4);
        efv[0] = e0.x; efv[1] = e0.y; efv[2] = e0.z; efv[3] = e0.w;
        efv[4] = e1.x; efv[5] = e1.y; efv[6] = e1.z; efv[7] = e1.w;
    }
#pragma unroll
    for (int o = 0; o < 16; o++) {
        int oc = quad * 16 + o;
        float a = 0.f;
#pragma unroll
        for (int b = 0; b < 8; b++) a += efv[b] * bf(w0s[b * 64 + oc]);
        h0[m16 * HS + oc] = fb(silu_f(a * 0.35355339059327373f));
    }
    __syncthreads();

    // ---- L1 (MFMA 16x16x32, K=64, N=64) ----
    const u16* w1p = Wr1T + t * 4096;
    short8 afr[2];
    afr[0] = *(const short8*)&h0[m16 * HS + quad * 8];
    afr[1] = *(const short8*)&h0[m16 * HS + 32 + quad * 8];
    {
        float4v acc[4];
#pragma unroll
        for (int nt = 0; nt < 4; nt++) {
            acc[nt] = (float4v){0.f, 0.f, 0.f, 0.f};
#pragma unroll
            for (int ks = 0; ks < 2; ks++) {
                short8 bfr = *(const short8*)&w1p[(nt * 16 + m16) * 64 + ks * 32 + quad * 8];
                acc[nt] = __builtin_amdgcn_mfma_f32_16x16x32_bf16(afr[ks], bfr, acc[nt], 0, 0, 0);
            }
        }
#pragma unroll
        for (int nt = 0; nt < 4; nt++)
#pragma unroll
            for (int r = 0; r < 4; r++)
                h1[(quad * 4 + r) * HS + nt * 16 + m16] = fb(silu_f(acc[nt][r] * 0.125f));
    }
    __syncthreads();

    // ---- L2 (MFMA, K=64, N=64) ----
    const u16* w2p = Wr2T + t * 4096;
    afr[0] = *(const short8*)&h1[m16 * HS + quad * 8];
    afr[1] = *(const short8*)&h1[m16 * HS + 32 + quad * 8];
    {
        float4v acc[4];
#pragma unroll
        for (int nt = 0; nt < 4; nt++) {
            acc[nt] = (float4v){0.f, 0.f, 0.f, 0.f};
#pragma unroll
            for (int ks = 0; ks < 2; ks++) {
                short8 bfr = *(const short8*)&w2p[(nt * 16 + m16) * 64 + ks * 32 + quad * 8];
                acc[nt] = __builtin_amdgcn_mfma_f32_16x16x32_bf16(afr[ks], bfr, acc[nt], 0, 0, 0);
            }
        }
#pragma unroll
        for (int nt = 0; nt < 4; nt++)
#pragma unroll
            for (int r = 0; r < 4; r++)
                h0[(quad * 4 + r) * HS + nt * 16 + m16] = fb(silu_f(acc[nt][r] * 0.125f));
    }
    __syncthreads();

    // ---- L3 (MFMA, K=64, N=512), chunked 4x128; staging aliases hbuf ----
    const u16* w3p = Wr3T + t * 32768;
    afr[0] = *(const short8*)&h0[m16 * HS + quad * 8];
    afr[1] = *(const short8*)&h0[m16 * HS + 32 + quad * 8];
    u16* stw = &hbuf[0];
    for (int cc = 0; cc < 4; cc++) {
#pragma unroll
        for (int nt8 = 0; nt8 < 8; nt8++) {
            int nt = cc * 8 + nt8;
            float4v a3 = (float4v){0.f, 0.f, 0.f, 0.f};
#pragma unroll
            for (int ks = 0; ks < 2; ks++) {
                short8 bfr = *(const short8*)&w3p[(nt * 16 + m16) * 64 + ks * 32 + quad * 8];
                a3 = __builtin_amdgcn_mfma_f32_16x16x32_bf16(afr[ks], bfr, a3, 0, 0, 0);
            }
#pragma unroll
            for (int r = 0; r < 4; r++)
                stw[(quad * 4 + r) * 136 + nt8 * 16 + m16] = fb(a3[r] * 0.125f);
        }
        __syncthreads();
        // l-major store: addr = (cc*N_EDGES + E0+edge)*128 + m16*8
        // lanes (quad, m16) for fixed st: 4 consecutive edges x 256B = 1KB contiguous
#pragma unroll
        for (int st = 0; st < 4; st++) {
            int edge = st * 4 + quad;
            uint4 v = *(const uint4*)&stw[edge * 136 + m16 * 8];
            *(uint4*)&tpw[((size_t)cc * N_EDGES + E0 + edge) * 128 + m16 * 8] = v;
        }
        __syncthreads();
    }
}
#undef HS

// ---------- message accumulation -> l-grouped global msg (bf16) ----------
// tpw is l-major: tpw[(l*N_EDGES + e)*128 + k]
__global__ __launch_bounds__(256) void k_msg(const int* offs, const int* sorted,
                                             const int* eidx, const float* esh,
                                             const u16* up, const u16* tpw, u16* msgA) {
    const int LM[16] = {0,1,1,1,2,2,2,2,2,3,3,3,3,3,3,3};
    int tid = threadIdx.x;
    int nsub = tid >> 5;
    int kq = tid & 31;
    int k4 = kq * 4;
    int n = blockIdx.x * 8 + nsub;

    float acc[16][4];
#pragma unroll
    for (int m = 0; m < 16; m++)
#pragma unroll
        for (int q = 0; q < 4; q++) acc[m][q] = 0.f;
    int s = offs[n], e1 = offs[n + 1];
    for (int idx = s; idx < e1; idx++) {
        int e = sorted[idx];
        int j = eidx[e];
        ushort4 uu = *(const ushort4*)(up + (size_t)j * 128 + k4);
        float u0 = bf(uu.x), u1 = bf(uu.y), u2 = bf(uu.z), u3 = bf(uu.w);
        float4 sA = *(const float4*)(esh + (size_t)e * 16);
        float4 sB = *(const float4*)(esh + (size_t)e * 16 + 4);
        float4 sC = *(const float4*)(esh + (size_t)e * 16 + 8);
        float4 sD = *(const float4*)(esh + (size_t)e * 16 + 12);
        float sh[16] = {sA.x, sA.y, sA.z, sA.w, sB.x, sB.y, sB.z, sB.w,
                        sC.x, sC.y, sC.z, sC.w, sD.x, sD.y, sD.z, sD.w};
        float p[4][4];
#pragma unroll
        for (int l = 0; l < 4; l++) {
            ushort4 tp = *(const ushort4*)(tpw + ((size_t)l * N_EDGES + e) * 128 + k4);
            p[l][0] = u0 * bf(tp.x); p[l][1] = u1 * bf(tp.y);
            p[l][2] = u2 * bf(tp.z); p[l][3] = u3 * bf(tp.w);
        }
#pragma unroll
        for (int m = 0; m < 16; m++) {
            int l = LM[m];
            acc[m][0] += sh[m] * p[l][0]; acc[m][1] += sh[m] * p[l][1];
            acc[m][2] += sh[m] * p[l][2]; acc[m][3] += sh[m] * p[l][3];
        }
    }
#pragma unroll
    for (int m = 0; m < 16; m++) {
        int row = RBc[m] + n * RSc[m];
        ushort4 o;
        o.x = fb(acc[m][0] * 0.1f); o.y = fb(acc[m][1] * 0.1f);
        o.z = fb(acc[m][2] * 0.1f); o.w = fb(acc[m][3] * 0.1f);
        *(ushort4*)(msgA + (size_t)row * 128 + k4) = o;
    }
}

// ---------- FUSED A-GEMM + invariants + product -> bvec (v2: no spill) ----------
__global__ __launch_bounds__(256) void k_gemmAb(int t, const u16* msgA, const u16* WlinT,
                                                const int* species,
                                                const u16* Wp1, const u16* Wp2, const u16* Wp3,
                                                u16* bvec) {
    __shared__ u16 wfr[16384];
    int tid = threadIdx.x;
    int wave = tid >> 6, lane = tid & 63;
    int m16 = lane & 15, quad = lane >> 4;
    int grp = wave >> 1;          // node group within block (0/1)
    int nth = wave & 1;           // channel half: nt = nth*4 + ntl
    int n0w = blockIdx.x * 32 + grp * 16;
    const float sAc = 0.08838834764831845f;

    float A0[4][4];
    float inv2[4][4][4];
#pragma unroll
    for (int l = 0; l < 4; l++)
#pragma unroll
        for (int ntl = 0; ntl < 4; ntl++)
#pragma unroll
            for (int r = 0; r < 4; r++) inv2[l][ntl][r] = 0.f;

    const int ms_[4] = {0, 1, 4, 9}, me_[4] = {1, 4, 9, 16};
#pragma unroll
    for (int l = 0; l < 4; l++) {
        __syncthreads();   // protect previous l's wfr reads
        const u16* wg = WlinT + ((size_t)t * 4 + l) * 16384;
#pragma unroll
        for (int p = 0; p < 8; p++) {
            int slot = p * 256 + tid;
            int nt = slot >> 8, ks = (slot >> 6) & 3, ln = slot & 63;
            int nn = nt * 16 + (ln & 15), k0 = ks * 32 + (ln >> 4) * 8;
            *(uint4*)&wfr[slot * 8] = *(const uint4*)&wg[nn * 128 + k0];
        }
        __syncthreads();
#pragma unroll
        for (int m = ms_[l]; m < me_[l]; m++) {
            int rowa = RBc[m] + (n0w + m16) * RSc[m];
            const u16* ap = msgA + (size_t)rowa * 128 + quad * 8;
            short8 afr[4];
#pragma unroll
            for (int ks = 0; ks < 4; ks++) afr[ks] = *(const short8*)(ap + ks * 32);
#pragma unroll
            for (int ntl = 0; ntl < 4; ntl++) {
                int nt = nth * 4 + ntl;
                float4v acc = (float4v){0.f, 0.f, 0.f, 0.f};
#pragma unroll
                for (int ks = 0; ks < 4; ks++) {
                    short8 bfr = *(const short8*)&wfr[((nt * 4 + ks) * 64 + lane) * 8];
                    acc = __builtin_amdgcn_mfma_f32_16x16x32_bf16(afr[ks], bfr, acc, 0, 0, 0);
                }
#pragma unroll
                for (int r = 0; r < 4; r++) {
                    float a = acc[r] * sAc;
                    if (m == 0) A0[ntl][r] = a;
                    inv2[l][ntl][r] += a * a;
                }
            }
        }
    }

    // ---- epilogue: b = w1*A0 + w2.inv2 + (w3.inv2)*A0 -> bvec ----
#pragma unroll
    for (int r = 0; r < 4; r++) {
        int n = n0w + quad * 4 + r;
        int sp = species[n];
        const u16* p1 = Wp1 + ((size_t)t * 10 + sp) * 128;
        const u16* p2 = Wp2 + ((size_t)t * 10 + sp) * 4 * 128;
        const u16* p3 = Wp3 + ((size_t)t * 10 + sp) * 4 * 128;
#pragma unroll
        for (int ntl = 0; ntl < 4; ntl++) {
            int ch = (nth * 4 + ntl) * 16 + m16;
            float w1 = bf(p1[ch]);
            float s2 = 0.f, s3 = 0.f;
#pragma unroll
            for (int l = 0; l < 4; l++) {
                s2 += bf(p2[l * 128 + ch]) * inv2[l][ntl][r];
                s3 += bf(p3[l * 128 + ch]) * inv2[l][ntl][r];
            }
            bvec[(size_t)n * 128 + ch] = fb(w1 * A0[ntl][r] + s2 + s3 * A0[ntl][r]);
        }
    }
}

// ---------- nf = bvec @ WplT / sqrt(128) + sc ----------
__global__ __launch_bounds__(256) void k_gemm_nf(int t, const u16* bvec, const u16* WplT,
                                                 const float* sc, float* nf) {
    __shared__ u16 wfr[16384];
    int rb0 = blockIdx.x * 64;
    int tid = threadIdx.x;
    const u16* wg = WplT + (size_t)t * 16384;
#pragma unroll
    for (int p = 0; p < 8; p++) {
        int slot = p * 256 + tid;
        int nt = slot >> 8, ks = (slot >> 6) & 3, ln = slot & 63;
        int nn = nt * 16 + (ln & 15), k0 = ks * 32 + (ln >> 4) * 8;
        *(uint4*)&wfr[slot * 8] = *(const uint4*)&wg[nn * 128 + k0];
    }
    __syncthreads();

    int wave = tid >> 6, lane = tid & 63;
    int m16 = lane & 15, quad = lane >> 4;
    int rowa = rb0 + wave * 16 + m16;
    const u16* ap = bvec + (size_t)rowa * 128 + quad * 8;
    short8 afr[4];
#pragma unroll
    for (int ks = 0; ks < 4; ks++) afr[ks] = *(const short8*)(ap + ks * 32);

    float4v acc[8];
#pragma unroll
    for (int nt = 0; nt < 8; nt++) acc[nt] = (float4v){0.f, 0.f, 0.f, 0.f};
#pragma unroll
    for (int nt = 0; nt < 8; nt++)
#pragma unroll
        for (int ks = 0; ks < 4; ks++) {
            short8 bfr = *(const short8*)&wfr[((nt * 4 + ks) * 64 + lane) * 8];
            acc[nt] = __builtin_amdgcn_mfma_f32_16x16x32_bf16(afr[ks], bfr, acc[nt], 0, 0, 0);
        }

    const float sAc = 0.08838834764831845f;
    int rowc = rb0 + wave * 16 + quad * 4;
#pragma unroll
    for (int nt = 0; nt < 8; nt++) {
        int col = nt * 16 + m16;
#pragma unroll
        for (int r = 0; r < 4; r++) {
            size_t idx = (size_t)(rowc + r) * 128 + col;
            nf[idx] = acc[nt][r] * sAc + sc[idx];
        }
    }
}

// ---------- graph readout: 8 nodes/block, register segment-sum + atomic flush ----------
__global__ __launch_bounds__(128) void k_reduce(const float* nf, const int* batch,
                                                float* env, float* cnt) {
    int k = threadIdx.x;
    int n0 = blockIdx.x * 8;
    float run = 0.f;
    int c = 0;
    int gp = batch[n0];
    for (int nn = 0; nn < 8; nn++) {
        int n = n0 + nn;
        int g = batch[n];
        if (g != gp) {
            atomicAdd(&env[gp * 128 + k], run);
            if (k == 0) atomicAdd(&cnt[gp], (float)c);
            run = 0.f; c = 0; gp = g;
        }
        run += nf[(size_t)n * 128 + k];
        c++;
    }
    atomicAdd(&env[gp * 128 + k], run);
    if (k == 0) atomicAdd(&cnt[gp], (float)c);
}

// ---------- final: output float32 ----------
__global__ void k_final(const float* env, const float* cnt, float* out) {
    int i = blockIdx.x * 256 + threadIdx.x;
    if (i < N_GRAPHS * 128) out[i] = env[i] / fmaxf(cnt[i >> 7], 1.f);
}

// ---------- launch ----------
extern "C" void kernel_launch(void* const* d_in, const int* in_sizes, int n_in,
                              void* d_out, int out_size, void* d_ws, size_t ws_size,
                              hipStream_t stream) {
    (void)in_sizes; (void)n_in; (void)out_size; (void)ws_size;
    const void* x    = d_in[0];
    const void* pos  = d_in[1];
    const int* eidx  = (const int*)d_in[14];
    const int* batch = (const int*)d_in[15];

    char* base = (char*)d_ws;
    size_t cur = 0;
    auto alloc = [&](size_t bytes) -> void* {
        void* p = base + cur;
        cur = (cur + bytes + 255) & ~(size_t)255;
        return p;
    };
    int*   flag    = (int*)alloc(4);
    u16*   cvt     = (u16*)alloc((size_t)631552 * 2);
    int*   species = (int*)alloc((size_t)N_NODES * 4);
    int*   shist   = (int*)alloc(64);
    int*   spoffs  = (int*)alloc(64);
    int*   spcursor= (int*)alloc(64);
    int*   perm    = (int*)alloc((size_t)N_NODES * 4);
    int*   hist    = (int*)alloc((size_t)N_NODES * 4);
    int*   offs    = (int*)alloc((size_t)(N_NODES + 1) * 4);
    int*   cursor  = (int*)alloc((size_t)N_NODES * 4);
    int*   sorted  = (int*)alloc((size_t)N_EDGES * 4);
    float* env     = (float*)alloc((size_t)N_GRAPHS * 128 * 4);
    float* cnt     = (float*)alloc((size_t)N_GRAPHS * 4);
    float* nf      = (float*)alloc((size_t)N_NODES * 128 * 4);
    u16*   up      = (u16*)alloc((size_t)N_NODES * 128 * 2);
    u16*   bvec    = (u16*)alloc((size_t)N_NODES * 128 * 2);
    float* sc      = (float*)alloc((size_t)N_NODES * 128 * 4);
    float* ef      = (float*)alloc((size_t)N_EDGES * 8 * 4);
    float* esh     = (float*)alloc((size_t)N_EDGES * 16 * 4);
    u16*   tpw     = (u16*)alloc((size_t)N_EDGES * 512 * 2);
    u16*   msgA    = (u16*)alloc((size_t)262144 * 128 * 2);

    static const int cn[12] = {1280, 32768, 1024, 8192, 8192, 65536,
                               131072, 327680, 2560, 10240, 10240, 32768};
    CvtArgs ca;
    size_t off[13]; off[0] = 0;
    for (int q = 0; q < 12; q++) { ca.src[q] = d_in[2 + q]; ca.n[q] = cn[q]; off[q + 1] = off[q] + cn[q]; }
    u16* cWemb  = cvt + off[0];
    u16* cWupT  = cvt + off[1];
    u16* cWr0   = cvt + off[2];
    u16* cWr1T  = cvt + off[3];
    u16* cWr2T  = cvt + off[4];
    u16* cWr3T  = cvt + off[5];
    u16* cWlinT = cvt + off[6];
    u16* cWskipT= cvt + off[7];
    u16* cWp1   = cvt + off[8];
    u16* cWp2   = cvt + off[9];
    u16* cWp3   = cvt + off[10];
    u16* cWplT  = cvt + off[11];

    k_detect<<<1, 256, 0, stream>>>(x, flag);
    k_convert<<<256, 256, 0, stream>>>(ca, cvt, flag);
    k_zero<<<64, 256, 0, stream>>>((float*)hist, N_NODES);
    k_zero<<<1, 64, 0, stream>>>((float*)shist, 16);
    k_zero<<<32, 256, 0, stream>>>(env, N_GRAPHS * 128);
    k_zero<<<1, 256, 0, stream>>>(cnt, N_GRAPHS);
    k_species<<<N_NODES / 256, 256, 0, stream>>>(x, species, shist, flag);
    k_embed<<<N_NODES * 128 / 256, 256, 0, stream>>>(species, cWemb, nf);
    k_spscan<<<1, 64, 0, stream>>>(shist, spoffs, spcursor);
    k_spsort<<<N_NODES / 256, 256, 0, stream>>>(species, spcursor, perm);
    k_prep_edges<<<N_EDGES / 256, 256, 0, stream>>>(eidx, pos, esh, ef, hist, flag);
    k_scan<<<1, 1024, 0, stream>>>(hist, offs, cursor);
    k_sort<<<N_EDGES / 256, 256, 0, stream>>>(eidx, cursor, sorted);

    for (int t = 0; t < 2; t++) {
        k_upsc<<<dim3(256, 10), 256, 0, stream>>>(t, nf, perm, spoffs, cWupT, cWskipT, up, sc);
        k_radial<<<N_EDGES / 16, 64, 0, stream>>>(t, ef, cWr0, cWr1T, cWr2T, cWr3T, tpw);
        k_msg<<<N_NODES / 8, 256, 0, stream>>>(offs, sorted, eidx, esh, up, tpw, msgA);
        k_gemmAb<<<N_NODES / 32, 256, 0, stream>>>(t, msgA, cWlinT, species,
                                                   cWp1, cWp2, cWp3, bvec);
        k_gemm_nf<<<N_NODES / 64, 256, 0, stream>>>(t, bvec, cWplT, sc, nf);
    }
    k_reduce<<<N_NODES / 8, 128, 0, stream>>>(nf, batch, env, cnt);
    k_final<<<32, 256, 0, stream>>>(env, cnt, (float*)d_out);
}